// Round 4
// baseline (6807.330 us; speedup 1.0000x reference)
//
#include <hip/hip_runtime.h>

// ---------------------------------------------------------------------------
// LanguageModel: embed -> LSTM(1024) x2 -> last-step logits(32000) -> softmax
// B=64, S=512, E=512, H=1024, G=4H=4096, V=32000
//
// Round 8 (single-hop barrier):
//  - Replaced 2-hop leader barrier (done-flags -> leader poll -> go-flag)
//    with ONE relaxed atomic counter per batch-half domain: each block adds 1
//    after its h stores drain; every block polls ctr >= 128*t. Removes one
//    full IF poll-observe round trip (~1us) from every step.
//  - vmcnt(0) drain only in wave 0 (all h stores are tid<32 = wave 0; tid 0's
//    counter add follows in wave-0 program order). One less __syncthreads.
//  - h1A store + next-step x4s prefetch moved AFTER the counter add: off the
//    critical path; xv prefetch overlaps the poll window.
//  - h-load batching (round 7) kept: 16 fragments hoisted before any MFMA.
// ---------------------------------------------------------------------------

#define BB 64
#define SS 512
#define EE 512
#define HH 1024
#define GG 4096
#define VV 32000

using bf16x8 = __attribute__((ext_vector_type(8))) __bf16;
using f32x4  = __attribute__((ext_vector_type(4))) float;

__device__ __forceinline__ unsigned short f2bf(float f) {
    unsigned u = __float_as_uint(f);
    unsigned r = u + 0x7FFFu + ((u >> 16) & 1u);   // RNE
    return (unsigned short)(r >> 16);
}
__device__ __forceinline__ float bf2f(unsigned short u) {
    return __uint_as_float(((unsigned)u) << 16);
}
__device__ __forceinline__ float sigm(float x) {
    return 1.0f / (1.0f + expf(-x));
}
// 16B fragment load via two agent-scope relaxed atomics (sc1 -> coherent at IF).
__device__ __forceinline__ bf16x8 ld_frag_coh(const unsigned long long* p) {
    union { unsigned long long u[2]; bf16x8 v; } x;
    x.u[0] = __hip_atomic_load(p,     __ATOMIC_RELAXED, __HIP_MEMORY_SCOPE_AGENT);
    x.u[1] = __hip_atomic_load(p + 1, __ATOMIC_RELAXED, __HIP_MEMORY_SCOPE_AGENT);
    return x.v;
}

// Packed-B layout: elem(nt, kt, lane, j) = B[kt*32 + (lane>>4)*8 + j][nt*16 + (lane&15)]
__global__ void pack_b(const float* __restrict__ B, unsigned short* __restrict__ out,
                       int KT, int N) {
    int bid = blockIdx.x;          // = nt*KT + kt
    int lane = threadIdx.x;
    int nt = bid / KT, kt = bid % KT;
    int k = kt * 32 + ((lane >> 4) << 3);
    int n = nt * 16 + (lane & 15);
    size_t base = ((size_t)bid * 64 + lane) * 8;
    #pragma unroll
    for (int j = 0; j < 8; ++j)
        out[base + j] = f2bf(B[(size_t)(k + j) * N + n]);
}

// Wh pack: colgroup g in [0,128) owns h-cols 8g..8g+7
// -> 32 gate-cols ordered n = q*8+cj (q=gate, cj=col offset), as 2 n-tiles.
// Frag id f = (g*2 + nt)*32 + kt.
__global__ void pack_wh(const float* __restrict__ Wh, unsigned short* __restrict__ out) {
    int f = blockIdx.x;            // (g*2 + nt)*32 + kt ; grid 8192
    int lane = threadIdx.x;
    int kt = f & 31, nt = (f >> 5) & 1, g = f >> 6;
    int nloc = lane & 15;
    int q = nt * 2 + (nloc >> 3), cj = nloc & 7;
    int gcol = q * HH + 8 * g + cj;
    int k = kt * 32 + ((lane >> 4) << 3);
    size_t base = ((size_t)f * 64 + lane) * 8;
    #pragma unroll
    for (int j = 0; j < 8; ++j)
        out[base + j] = f2bf(Wh[(size_t)(k + j) * GG + gcol]);
}

// Embedding gather written directly in packed-A form (M=32768 rows, K=512).
// Row order r = s*64 + b  (s-major, batch innermost).
__global__ void embed_pack(const int* __restrict__ x, const float* __restrict__ tab,
                           unsigned short* __restrict__ out) {
    int bid = blockIdx.x;          // = mt*16 + kt  (KT=16)
    int lane = threadIdx.x;
    int mt = bid >> 4, kt = bid & 15;
    int m = mt * 16 + (lane & 15);            // r = s*64 + b
    int idx = x[(m & 63) * SS + (m >> 6)];    // x is [B][S]
    int kb = kt * 32 + ((lane >> 4) << 3);
    size_t base = ((size_t)bid * 64 + lane) * 8;
    const float* src = tab + (size_t)idx * EE + kb;
    #pragma unroll
    for (int j = 0; j < 8; ++j)
        out[base + j] = f2bf(src[j]);
}

// C = A@B + bias.  MODE 0: float row-major (logits).
//                  MODE 1: bf16 x4s layout out[((s*GG + col)*64 + batch)],
//                          virtual row r = s*64 + batch; block owns one s x
//                          64 cols x 64 batches = contiguous 8KB region.
template<int MODE>
__global__ __launch_bounds__(256) void gemm_bias(
    const unsigned short* __restrict__ Ap, const unsigned short* __restrict__ Bp,
    const float* __restrict__ bias, void* __restrict__ Cout, int N, int KT) {
    __shared__ unsigned short tile[64][72];   // MODE1 transpose staging (padded)
    const int tid = threadIdx.x, lane = tid & 63, w = tid >> 6;
    const int ntg = blockIdx.x * 4 + w;
    const int m0t = blockIdx.y * 4;
    const bf16x8* Av = reinterpret_cast<const bf16x8*>(Ap);
    const bf16x8* Bv = reinterpret_cast<const bf16x8*>(Bp);
    f32x4 acc[4] = {{0.f,0.f,0.f,0.f},{0.f,0.f,0.f,0.f},{0.f,0.f,0.f,0.f},{0.f,0.f,0.f,0.f}};
    for (int kt = 0; kt < KT; ++kt) {
        bf16x8 b = Bv[((size_t)ntg * KT + kt) * 64 + lane];
        #pragma unroll
        for (int mt = 0; mt < 4; ++mt) {
            bf16x8 a = Av[((size_t)(m0t + mt) * KT + kt) * 64 + lane];
            acc[mt] = __builtin_amdgcn_mfma_f32_16x16x32_bf16(a, b, acc[mt], 0, 0, 0);
        }
    }
    const int col = ntg * 16 + (lane & 15);
    const int rq = (lane >> 4) << 2;
    const float bb = bias[col];
    if (MODE == 0) {
        #pragma unroll
        for (int mt = 0; mt < 4; ++mt)
            #pragma unroll
            for (int i = 0; i < 4; ++i) {
                int row = (m0t + mt) * 16 + rq + i;
                ((float*)Cout)[(size_t)row * N + col] = acc[mt][i] + bb;
            }
    } else {
        const int cl = w * 16 + (lane & 15);            // block-local col
        #pragma unroll
        for (int mt = 0; mt < 4; ++mt)
            #pragma unroll
            for (int i = 0; i < 4; ++i)
                tile[cl][mt * 16 + rq + i] = f2bf(acc[mt][i] + bb);
        __syncthreads();
        // linear 8KB store: out element (s*GG + col0)*64 + c*64 + b
        const int c = tid >> 2, b0 = (tid & 3) << 4;
        unsigned short* dst = (unsigned short*)Cout +
            ((size_t)blockIdx.y * GG + (size_t)blockIdx.x * 64) * 64 + (size_t)tid * 16;
        const uint4* s4 = reinterpret_cast<const uint4*>(&tile[c][b0]);
        reinterpret_cast<uint4*>(dst)[0] = s4[0];
        reinterpret_cast<uint4*>(dst)[1] = s4[1];
    }
}

// Zero h0 for both layers + all barrier counters.
__global__ void zero_init(unsigned short* __restrict__ h0a,
                          unsigned short* __restrict__ h0b,
                          unsigned int* __restrict__ flags) {
    int i = blockIdx.x * 256 + threadIdx.x;      // grid 64 x 256
    for (int k = i; k < BB * HH; k += 64 * 256) { h0a[k] = 0; h0b[k] = 0; }
    for (int k = i; k < 8256; k += 64 * 256) flags[k] = 0;
}

// Persistent LSTM layer. Grid 256 x 256 (cooperative).
// Block b: g = b>>1 (h-cols 8g..8g+7 -> 32 gate-cols), hf = b&1 (batch rows 32hf..+31).
// Waves: msub = w&1 (row-tile), kh = w>>1 (K-half) -> disjoint A fragments.
// Barrier: single-hop counter. Each block atomicAdds 1 to its domain counter
// after its h stores drain; all blocks poll ctr >= 128*t.
__global__ __launch_bounds__(256, 1) void lstm_layer(
    const unsigned short* __restrict__ x4s, const unsigned short* __restrict__ whp,
    unsigned short* __restrict__ hbA, unsigned short* __restrict__ hbB,
    unsigned short* __restrict__ h1A, unsigned int* __restrict__ ctrL) {
    __shared__ float gx[2][32][36];                         // [khalf][n][block-row]
    __shared__ __align__(16) unsigned short hlds[32][8];    // gathered h chunks
    __shared__ __align__(16) unsigned short Blds[128 * 64 * 8];  // 64 KB Wh slice
    const int tid = threadIdx.x, lane = tid & 63, w = tid >> 6;
    const int g = blockIdx.x >> 1, hf = blockIdx.x & 1;
    unsigned int* ctr = ctrL + hf * 16;                     // 64B-padded counter

    // ---- stage this colgroup's Wh slice (64 KB) into LDS, once ----
    {
        const uint4* src = reinterpret_cast<const uint4*>(whp) + (size_t)g * 4096;
        uint4* dst = reinterpret_cast<uint4*>(Blds);
        #pragma unroll
        for (int i = 0; i < 16; ++i)
            dst[i * 256 + tid] = src[i * 256 + tid];
    }
    __syncthreads();
    const bf16x8* Bl = reinterpret_cast<const bf16x8*>(Blds);

    const int msub = w & 1, kh = w >> 1;
    const int kh16 = kh * 16;
    const int nloc = lane & 15;
    const int cj = nloc & 7;
    const int q0 = nloc >> 3;                               // gate idx for nt=0
    const int gq0 = q0 * HH + 8 * g + cj;                   // nt=0 gate col
    const int gq1 = (2 + q0) * HH + 8 * g + cj;             // nt=1 gate col
    const int rbase = msub * 16 + ((lane >> 4) << 2);       // block-local row base
    const size_t afrag_base = ((size_t)(2 * hf + msub) * 32 + (size_t)kh * 16) * 64 + lane;

    // elementwise thread mapping
    const int row_l = tid >> 3, cj2 = tid & 7;
    float c = 0.f;

    // prologue: x4s prefetch for t=0
    ushort4 xv0 = {0, 0, 0, 0}, xv1 = {0, 0, 0, 0};
    if (kh == 0) {
        xv0 = *reinterpret_cast<const ushort4*>(x4s + ((size_t)gq0) * 64 + 32 * hf + rbase);
        xv1 = *reinterpret_cast<const ushort4*>(x4s + ((size_t)gq1) * 64 + 32 * hf + rbase);
    }

    #pragma unroll 1
    for (int t = 0; t < SS; ++t) {
        // ---- single-hop wait: all 128 producer blocks of this domain done t-1 ----
        if (t > 0) {
            if (tid == 0) {
                const unsigned tgt = (unsigned)t * 128u;
                while (__hip_atomic_load(ctr, __ATOMIC_RELAXED,
                                         __HIP_MEMORY_SCOPE_AGENT) < tgt)
                    __builtin_amdgcn_s_sleep(1);
            }
            __syncthreads();
        }

        const unsigned long long* hv =
            reinterpret_cast<const unsigned long long*>((t & 1) ? hbB : hbA);
        unsigned short* hout = (t & 1) ? hbA : hbB;

        // ---- hoisted h-loads: all 16 fragments before any MFMA (1 window) ----
        bf16x8 A[16];
        #pragma unroll
        for (int k = 0; k < 16; ++k)
            A[k] = ld_frag_coh(hv + (afrag_base + (size_t)k * 64) * 2);

        f32x4 acc0 = {0.f, 0.f, 0.f, 0.f}, acc1 = {0.f, 0.f, 0.f, 0.f};
        #pragma unroll
        for (int k = 0; k < 16; ++k) {
            acc0 = __builtin_amdgcn_mfma_f32_16x16x32_bf16(
                A[k], Bl[(kh16 + k) * 64 + lane], acc0, 0, 0, 0);
            acc1 = __builtin_amdgcn_mfma_f32_16x16x32_bf16(
                A[k], Bl[(32 + kh16 + k) * 64 + lane], acc1, 0, 0, 0);
        }

        // write K-half partial sums (kh0 adds the x-projection, prefetched)
        if (kh == 0) {
            gx[0][nloc][rbase + 0] = acc0[0] + bf2f(xv0.x);
            gx[0][nloc][rbase + 1] = acc0[1] + bf2f(xv0.y);
            gx[0][nloc][rbase + 2] = acc0[2] + bf2f(xv0.z);
            gx[0][nloc][rbase + 3] = acc0[3] + bf2f(xv0.w);
            gx[0][16 + nloc][rbase + 0] = acc1[0] + bf2f(xv1.x);
            gx[0][16 + nloc][rbase + 1] = acc1[1] + bf2f(xv1.y);
            gx[0][16 + nloc][rbase + 2] = acc1[2] + bf2f(xv1.z);
            gx[0][16 + nloc][rbase + 3] = acc1[3] + bf2f(xv1.w);
        } else {
            gx[1][nloc][rbase + 0] = acc0[0];
            gx[1][nloc][rbase + 1] = acc0[1];
            gx[1][nloc][rbase + 2] = acc0[2];
            gx[1][nloc][rbase + 3] = acc0[3];
            gx[1][16 + nloc][rbase + 0] = acc1[0];
            gx[1][16 + nloc][rbase + 1] = acc1[1];
            gx[1][16 + nloc][rbase + 2] = acc1[2];
            gx[1][16 + nloc][rbase + 3] = acc1[3];
        }
        __syncthreads();

        // elementwise: thread -> (row_l, cj2); n = q*8 + cj
        float gi = gx[0][0 * 8 + cj2][row_l] + gx[1][0 * 8 + cj2][row_l];
        float gf = gx[0][1 * 8 + cj2][row_l] + gx[1][1 * 8 + cj2][row_l];
        float gg = gx[0][2 * 8 + cj2][row_l] + gx[1][2 * 8 + cj2][row_l];
        float go = gx[0][3 * 8 + cj2][row_l] + gx[1][3 * 8 + cj2][row_l];
        float cn = sigm(gf) * c + sigm(gi) * tanhf(gg);
        c = cn;
        hlds[row_l][cj2] = f2bf(sigm(go) * tanhf(cn));
        __syncthreads();

        // gather 16B chunks; one full line per 4 rows, all owned by this block
        if (tid < 32) {
            union { uint4 v; unsigned long long u[2]; } cv;
            cv.v = *reinterpret_cast<const uint4*>(&hlds[tid][0]);
            const int m = 32 * hf + tid;
            unsigned long long* dst = reinterpret_cast<unsigned long long*>(
                hout + (((size_t)(m >> 4) * 32 + (g >> 2)) * 64 + (g & 3) * 16 + (m & 15)) * 8);
            __hip_atomic_store(dst,     cv.u[0], __ATOMIC_RELAXED, __HIP_MEMORY_SCOPE_AGENT);
            __hip_atomic_store(dst + 1, cv.u[1], __ATOMIC_RELAXED, __HIP_MEMORY_SCOPE_AGENT);
        }
        // all h stores are in wave 0; drain there, then notify (program order)
        if (w == 0)
            asm volatile("s_waitcnt vmcnt(0)" ::: "memory");
        if (tid == 0)
            (void)__hip_atomic_fetch_add(ctr, 1u, __ATOMIC_RELAXED,
                                         __HIP_MEMORY_SCOPE_AGENT);

        // ---- off-critical-path tail: h1A history store + next-step xv ----
        if (h1A && tid < 32) {
            union { uint4 v; unsigned long long u[2]; } cv;
            cv.v = *reinterpret_cast<const uint4*>(&hlds[tid][0]);
            const int m = 32 * hf + tid;
            const size_t mg = (size_t)t * 64 + m;   // packed-A row r = t*64 + m
            *reinterpret_cast<uint4*>(
                h1A + (((mg >> 4) * 32 + (size_t)(g >> 2)) * 64 + (g & 3) * 16 + (mg & 15)) * 8) = cv.v;
        }
        if (kh == 0 && t + 1 < SS) {
            xv0 = *reinterpret_cast<const ushort4*>(
                x4s + ((size_t)(t + 1) * GG + gq0) * 64 + 32 * hf + rbase);
            xv1 = *reinterpret_cast<const ushort4*>(
                x4s + ((size_t)(t + 1) * GG + gq1) * 64 + 32 * hf + rbase);
        }
    }
}

__global__ __launch_bounds__(256) void softmax_rows(const float* __restrict__ logits,
                                                    float* __restrict__ out) {
    __shared__ float red[256];
    int rr = blockIdx.x, tid = threadIdx.x;
    const float* L = logits + (size_t)rr * VV;
    float m = -1e30f;
    for (int i = tid; i < VV; i += 256) m = fmaxf(m, L[i]);
    red[tid] = m; __syncthreads();
    for (int s = 128; s > 0; s >>= 1) { if (tid < s) red[tid] = fmaxf(red[tid], red[tid + s]); __syncthreads(); }
    m = red[0]; __syncthreads();
    float sum = 0.f;
    for (int i = tid; i < VV; i += 256) sum += expf(L[i] - m);
    red[tid] = sum; __syncthreads();
    for (int s = 128; s > 0; s >>= 1) { if (tid < s) red[tid] += red[tid + s]; __syncthreads(); }
    float inv = 1.f / red[0];
    for (int i = tid; i < VV; i += 256) out[(size_t)rr * VV + i] = expf(L[i] - m) * inv;
}

extern "C" void kernel_launch(void* const* d_in, const int* in_sizes, int n_in,
                              void* d_out, int out_size, void* d_ws, size_t ws_size,
                              hipStream_t stream) {
    const int*   x    = (const int*)  d_in[0];
    const float* tab  = (const float*)d_in[1];
    const float* Wx0  = (const float*)d_in[2];
    const float* Wh0  = (const float*)d_in[3];
    const float* b0   = (const float*)d_in[4];
    const float* Wx1  = (const float*)d_in[5];
    const float* Wh1  = (const float*)d_in[6];
    const float* b1   = (const float*)d_in[7];
    const float* Wout = (const float*)d_in[8];
    const float* bout = (const float*)d_in[9];
    float* out = (float*)d_out;

    // ---- workspace layout (ushort units); all segments 16B-aligned ----
    unsigned short* ws    = (unsigned short*)d_ws;
    unsigned short* embA  = ws;                    // 16,777,216
    unsigned short* wx0p  = embA  + 16777216;      //  2,097,152
    unsigned short* wh0p  = wx0p  + 2097152;       //  4,194,304
    unsigned short* wx1p  = wh0p  + 4194304;       //  4,194,304
    unsigned short* wh1p  = wx1p  + 4194304;       //  4,194,304
    unsigned short* woutp = wh1p  + 4194304;       // 32,768,000
    unsigned short* x4s   = woutp + 32768000;      // 134,217,728 (reused by both layers)
    unsigned short* h1A   = x4s   + 134217728;     // 33,554,432
    unsigned short* hb0   = h1A   + 33554432;      // 65,536  (layer 0)
    unsigned short* hb1   = hb0   + 65536;         // 65,536
    unsigned short* hb2   = hb1   + 65536;         // 65,536  (layer 1)
    unsigned short* hb3   = hb2   + 65536;         // 65,536
    float* logits = (float*)(hb3 + 65536);         // 2,048,000 f32
    unsigned int* flags = (unsigned int*)(logits + 2048000);  // counters at +8192
    // total ~472 MB

    // ---- weight packing ----
    pack_b <<<256 * 16, 64, 0, stream>>>(Wx0, wx0p, 16, GG);
    pack_wh<<<8192, 64, 0, stream>>>(Wh0, wh0p);
    pack_b <<<256 * 32, 64, 0, stream>>>(Wx1, wx1p, 32, GG);
    pack_wh<<<8192, 64, 0, stream>>>(Wh1, wh1p);
    pack_b <<<2000 * 32, 64, 0, stream>>>(Wout, woutp, 32, VV);

    // ---- h0 + counter init ----
    zero_init<<<64, 256, 0, stream>>>(hb0, hb2, flags);

    // ---- embedding + layer-0 input projection ----
    embed_pack<<<32768, 64, 0, stream>>>(x, tab, embA);
    gemm_bias<1><<<dim3(GG / 64, 32768 / 64), 256, 0, stream>>>(embA, wx0p, b0, x4s, GG, EE / 32);

    // ---- layer 0 recurrence (persistent cooperative) ----
    {
        const unsigned short* a0 = x4s; const unsigned short* a1 = wh0p;
        unsigned short *a2 = hb0, *a3 = hb1, *a4 = h1A;
        unsigned int* a5 = flags + 8192;           // 2 counters (hf0/hf1), 64B pad
        void* args[] = {&a0, &a1, &a2, &a3, &a4, &a5};
        hipLaunchCooperativeKernel((const void*)lstm_layer, dim3(256), dim3(256),
                                   args, 0, stream);
    }

    // ---- layer-1 input projection + recurrence ----
    gemm_bias<1><<<dim3(GG / 64, 32768 / 64), 256, 0, stream>>>(h1A, wx1p, b1, x4s, GG, HH / 32);
    {
        const unsigned short* a0 = x4s; const unsigned short* a1 = wh1p;
        unsigned short *a2 = hb2, *a3 = hb3, *a4 = nullptr;
        unsigned int* a5 = flags + 8192 + 32;      // layer-1 counters
        void* args[] = {&a0, &a1, &a2, &a3, &a4, &a5};
        hipLaunchCooperativeKernel((const void*)lstm_layer, dim3(256), dim3(256),
                                   args, 0, stream);
    }
    // t=511 (odd) writes hb2

    // ---- logits (last timestep) + softmax ----
    gemm_bias<0><<<dim3(VV / 64, 1), 256, 0, stream>>>(hb2, woutp, bout, logits, VV, HH / 32);
    softmax_rows<<<64, 256, 0, stream>>>(logits, out);
}

// Round 5
// 5692.073 us; speedup vs baseline: 1.1959x; 1.1959x over previous
//
#include <hip/hip_runtime.h>

// ---------------------------------------------------------------------------
// LanguageModel: embed -> LSTM(1024) x2 -> last-step logits(32000) -> softmax
// B=64, S=512, E=512, H=1024, G=4H=4096, V=32000
//
// Round 9 (revert round-8 counter barrier; trim the proven round-7 path):
//  - Round-8 regression root cause: 128 atomicAdds serialize on ONE IF line
//    (~10ns each ~= +1.2us/step) + 256 pollers contending the same line.
//    Reverted to round-7's 2-hop leader barrier (128 independent flag lines).
//  - Wave-0-only drain: all h stores are wave 0's; removed the block-wide
//    __syncthreads + all-wave vmcnt(0) before the done-flag store.
//  - h1A history store moved to WAVE 1: its ~900cy HBM store-ack no longer
//    sits inside the wave-0 vmcnt(0) drain that gates the done-flag.
//  - Leader: ONE wave (tid<64) polls 2 flags/lane with __all, lane 0 stores
//    go immediately (no syncthreads between observe and publish).
//  - xv prefetch stays off-path (after flag store, consumed next step).
// ---------------------------------------------------------------------------

#define BB 64
#define SS 512
#define EE 512
#define HH 1024
#define GG 4096
#define VV 32000

using bf16x8 = __attribute__((ext_vector_type(8))) __bf16;
using f32x4  = __attribute__((ext_vector_type(4))) float;

__device__ __forceinline__ unsigned short f2bf(float f) {
    unsigned u = __float_as_uint(f);
    unsigned r = u + 0x7FFFu + ((u >> 16) & 1u);   // RNE
    return (unsigned short)(r >> 16);
}
__device__ __forceinline__ float bf2f(unsigned short u) {
    return __uint_as_float(((unsigned)u) << 16);
}
__device__ __forceinline__ float sigm(float x) {
    return 1.0f / (1.0f + expf(-x));
}
// 16B fragment load via two agent-scope relaxed atomics (sc1 -> coherent at IF).
__device__ __forceinline__ bf16x8 ld_frag_coh(const unsigned long long* p) {
    union { unsigned long long u[2]; bf16x8 v; } x;
    x.u[0] = __hip_atomic_load(p,     __ATOMIC_RELAXED, __HIP_MEMORY_SCOPE_AGENT);
    x.u[1] = __hip_atomic_load(p + 1, __ATOMIC_RELAXED, __HIP_MEMORY_SCOPE_AGENT);
    return x.v;
}

// Packed-B layout: elem(nt, kt, lane, j) = B[kt*32 + (lane>>4)*8 + j][nt*16 + (lane&15)]
__global__ void pack_b(const float* __restrict__ B, unsigned short* __restrict__ out,
                       int KT, int N) {
    int bid = blockIdx.x;          // = nt*KT + kt
    int lane = threadIdx.x;
    int nt = bid / KT, kt = bid % KT;
    int k = kt * 32 + ((lane >> 4) << 3);
    int n = nt * 16 + (lane & 15);
    size_t base = ((size_t)bid * 64 + lane) * 8;
    #pragma unroll
    for (int j = 0; j < 8; ++j)
        out[base + j] = f2bf(B[(size_t)(k + j) * N + n]);
}

// Wh pack: colgroup g in [0,128) owns h-cols 8g..8g+7
// -> 32 gate-cols ordered n = q*8+cj (q=gate, cj=col offset), as 2 n-tiles.
// Frag id f = (g*2 + nt)*32 + kt.
__global__ void pack_wh(const float* __restrict__ Wh, unsigned short* __restrict__ out) {
    int f = blockIdx.x;            // (g*2 + nt)*32 + kt ; grid 8192
    int lane = threadIdx.x;
    int kt = f & 31, nt = (f >> 5) & 1, g = f >> 6;
    int nloc = lane & 15;
    int q = nt * 2 + (nloc >> 3), cj = nloc & 7;
    int gcol = q * HH + 8 * g + cj;
    int k = kt * 32 + ((lane >> 4) << 3);
    size_t base = ((size_t)f * 64 + lane) * 8;
    #pragma unroll
    for (int j = 0; j < 8; ++j)
        out[base + j] = f2bf(Wh[(size_t)(k + j) * GG + gcol]);
}

// Embedding gather written directly in packed-A form (M=32768 rows, K=512).
// Row order r = s*64 + b  (s-major, batch innermost).
__global__ void embed_pack(const int* __restrict__ x, const float* __restrict__ tab,
                           unsigned short* __restrict__ out) {
    int bid = blockIdx.x;          // = mt*16 + kt  (KT=16)
    int lane = threadIdx.x;
    int mt = bid >> 4, kt = bid & 15;
    int m = mt * 16 + (lane & 15);            // r = s*64 + b
    int idx = x[(m & 63) * SS + (m >> 6)];    // x is [B][S]
    int kb = kt * 32 + ((lane >> 4) << 3);
    size_t base = ((size_t)bid * 64 + lane) * 8;
    const float* src = tab + (size_t)idx * EE + kb;
    #pragma unroll
    for (int j = 0; j < 8; ++j)
        out[base + j] = f2bf(src[j]);
}

// C = A@B + bias.  MODE 0: float row-major (logits).
//                  MODE 1: bf16 x4s layout out[((s*GG + col)*64 + batch)],
//                          virtual row r = s*64 + batch; block owns one s x
//                          64 cols x 64 batches = contiguous 8KB region.
template<int MODE>
__global__ __launch_bounds__(256) void gemm_bias(
    const unsigned short* __restrict__ Ap, const unsigned short* __restrict__ Bp,
    const float* __restrict__ bias, void* __restrict__ Cout, int N, int KT) {
    __shared__ unsigned short tile[64][72];   // MODE1 transpose staging (padded)
    const int tid = threadIdx.x, lane = tid & 63, w = tid >> 6;
    const int ntg = blockIdx.x * 4 + w;
    const int m0t = blockIdx.y * 4;
    const bf16x8* Av = reinterpret_cast<const bf16x8*>(Ap);
    const bf16x8* Bv = reinterpret_cast<const bf16x8*>(Bp);
    f32x4 acc[4] = {{0.f,0.f,0.f,0.f},{0.f,0.f,0.f,0.f},{0.f,0.f,0.f,0.f},{0.f,0.f,0.f,0.f}};
    for (int kt = 0; kt < KT; ++kt) {
        bf16x8 b = Bv[((size_t)ntg * KT + kt) * 64 + lane];
        #pragma unroll
        for (int mt = 0; mt < 4; ++mt) {
            bf16x8 a = Av[((size_t)(m0t + mt) * KT + kt) * 64 + lane];
            acc[mt] = __builtin_amdgcn_mfma_f32_16x16x32_bf16(a, b, acc[mt], 0, 0, 0);
        }
    }
    const int col = ntg * 16 + (lane & 15);
    const int rq = (lane >> 4) << 2;
    const float bb = bias[col];
    if (MODE == 0) {
        #pragma unroll
        for (int mt = 0; mt < 4; ++mt)
            #pragma unroll
            for (int i = 0; i < 4; ++i) {
                int row = (m0t + mt) * 16 + rq + i;
                ((float*)Cout)[(size_t)row * N + col] = acc[mt][i] + bb;
            }
    } else {
        const int cl = w * 16 + (lane & 15);            // block-local col
        #pragma unroll
        for (int mt = 0; mt < 4; ++mt)
            #pragma unroll
            for (int i = 0; i < 4; ++i)
                tile[cl][mt * 16 + rq + i] = f2bf(acc[mt][i] + bb);
        __syncthreads();
        // linear 8KB store: out element (s*GG + col0)*64 + c*64 + b
        const int c = tid >> 2, b0 = (tid & 3) << 4;
        unsigned short* dst = (unsigned short*)Cout +
            ((size_t)blockIdx.y * GG + (size_t)blockIdx.x * 64) * 64 + (size_t)tid * 16;
        const uint4* s4 = reinterpret_cast<const uint4*>(&tile[c][b0]);
        reinterpret_cast<uint4*>(dst)[0] = s4[0];
        reinterpret_cast<uint4*>(dst)[1] = s4[1];
    }
}

// Zero h0 for both layers + all barrier flags (incl. go-flags at [8192,8256)).
__global__ void zero_init(unsigned short* __restrict__ h0a,
                          unsigned short* __restrict__ h0b,
                          unsigned int* __restrict__ flags) {
    int i = blockIdx.x * 256 + threadIdx.x;      // grid 64 x 256
    for (int k = i; k < BB * HH; k += 64 * 256) { h0a[k] = 0; h0b[k] = 0; }
    for (int k = i; k < 8256; k += 64 * 256) flags[k] = 0;
}

// Persistent LSTM layer. Grid 256 x 256 (cooperative).
// Block b: g = b>>1 (h-cols 8g..8g+7 -> 32 gate-cols), hf = b&1 (batch rows 32hf..+31).
// Waves: msub = w&1 (row-tile), kh = w>>1 (K-half) -> disjoint A fragments.
// Barrier: per-block done-flags; leader (g==0) wave 0 polls all 128 (2/lane),
// lane 0 publishes a single go-flag everyone else polls (2-hop).
__global__ __launch_bounds__(256, 1) void lstm_layer(
    const unsigned short* __restrict__ x4s, const unsigned short* __restrict__ whp,
    unsigned short* __restrict__ hbA, unsigned short* __restrict__ hbB,
    unsigned short* __restrict__ h1A, unsigned int* __restrict__ flagsL,
    unsigned int* __restrict__ gofL) {
    __shared__ float gx[2][32][36];                         // [khalf][n][block-row]
    __shared__ __align__(16) unsigned short hlds[32][8];    // gathered h chunks
    __shared__ __align__(16) unsigned short Blds[128 * 64 * 8];  // 64 KB Wh slice
    const int tid = threadIdx.x, lane = tid & 63, w = tid >> 6;
    const int g = blockIdx.x >> 1, hf = blockIdx.x & 1;
    unsigned int* flags = flagsL + hf * 2048;               // 128 flags x 16 u32 pad
    unsigned int* gof = gofL + hf * 16;                     // 1 go-flag per domain

    // ---- stage this colgroup's Wh slice (64 KB) into LDS, once ----
    {
        const uint4* src = reinterpret_cast<const uint4*>(whp) + (size_t)g * 4096;
        uint4* dst = reinterpret_cast<uint4*>(Blds);
        #pragma unroll
        for (int i = 0; i < 16; ++i)
            dst[i * 256 + tid] = src[i * 256 + tid];
    }
    __syncthreads();
    const bf16x8* Bl = reinterpret_cast<const bf16x8*>(Blds);

    const int msub = w & 1, kh = w >> 1;
    const int kh16 = kh * 16;
    const int nloc = lane & 15;
    const int cj = nloc & 7;
    const int q0 = nloc >> 3;                               // gate idx for nt=0
    const int gq0 = q0 * HH + 8 * g + cj;                   // nt=0 gate col
    const int gq1 = (2 + q0) * HH + 8 * g + cj;             // nt=1 gate col
    const int rbase = msub * 16 + ((lane >> 4) << 2);       // block-local row base
    const size_t afrag_base = ((size_t)(2 * hf + msub) * 32 + (size_t)kh * 16) * 64 + lane;

    // elementwise thread mapping
    const int row_l = tid >> 3, cj2 = tid & 7;
    float c = 0.f;

    // prologue: x4s prefetch for t=0
    ushort4 xv0 = {0, 0, 0, 0}, xv1 = {0, 0, 0, 0};
    if (kh == 0) {
        xv0 = *reinterpret_cast<const ushort4*>(x4s + ((size_t)gq0) * 64 + 32 * hf + rbase);
        xv1 = *reinterpret_cast<const ushort4*>(x4s + ((size_t)gq1) * 64 + 32 * hf + rbase);
    }

    #pragma unroll 1
    for (int t = 0; t < SS; ++t) {
        const unsigned long long* hv =
            reinterpret_cast<const unsigned long long*>((t & 1) ? hbB : hbA);
        unsigned short* hout = (t & 1) ? hbA : hbB;

        // ---- hoisted h-loads: all 16 fragments before any MFMA (1 window) ----
        bf16x8 A[16];
        #pragma unroll
        for (int k = 0; k < 16; ++k)
            A[k] = ld_frag_coh(hv + (afrag_base + (size_t)k * 64) * 2);

        f32x4 acc0 = {0.f, 0.f, 0.f, 0.f}, acc1 = {0.f, 0.f, 0.f, 0.f};
        #pragma unroll
        for (int k = 0; k < 16; ++k) {
            acc0 = __builtin_amdgcn_mfma_f32_16x16x32_bf16(
                A[k], Bl[(kh16 + k) * 64 + lane], acc0, 0, 0, 0);
            acc1 = __builtin_amdgcn_mfma_f32_16x16x32_bf16(
                A[k], Bl[(32 + kh16 + k) * 64 + lane], acc1, 0, 0, 0);
        }

        // write K-half partial sums (kh0 adds the x-projection, prefetched)
        if (kh == 0) {
            gx[0][nloc][rbase + 0] = acc0[0] + bf2f(xv0.x);
            gx[0][nloc][rbase + 1] = acc0[1] + bf2f(xv0.y);
            gx[0][nloc][rbase + 2] = acc0[2] + bf2f(xv0.z);
            gx[0][nloc][rbase + 3] = acc0[3] + bf2f(xv0.w);
            gx[0][16 + nloc][rbase + 0] = acc1[0] + bf2f(xv1.x);
            gx[0][16 + nloc][rbase + 1] = acc1[1] + bf2f(xv1.y);
            gx[0][16 + nloc][rbase + 2] = acc1[2] + bf2f(xv1.z);
            gx[0][16 + nloc][rbase + 3] = acc1[3] + bf2f(xv1.w);
        } else {
            gx[1][nloc][rbase + 0] = acc0[0];
            gx[1][nloc][rbase + 1] = acc0[1];
            gx[1][nloc][rbase + 2] = acc0[2];
            gx[1][nloc][rbase + 3] = acc0[3];
            gx[1][16 + nloc][rbase + 0] = acc1[0];
            gx[1][16 + nloc][rbase + 1] = acc1[1];
            gx[1][16 + nloc][rbase + 2] = acc1[2];
            gx[1][16 + nloc][rbase + 3] = acc1[3];
        }
        __syncthreads();

        // elementwise: thread -> (row_l, cj2); n = q*8 + cj
        float gi = gx[0][0 * 8 + cj2][row_l] + gx[1][0 * 8 + cj2][row_l];
        float gf = gx[0][1 * 8 + cj2][row_l] + gx[1][1 * 8 + cj2][row_l];
        float gg = gx[0][2 * 8 + cj2][row_l] + gx[1][2 * 8 + cj2][row_l];
        float go = gx[0][3 * 8 + cj2][row_l] + gx[1][3 * 8 + cj2][row_l];
        float cn = sigm(gf) * c + sigm(gi) * tanhf(gg);
        c = cn;
        hlds[row_l][cj2] = f2bf(sigm(go) * tanhf(cn));
        __syncthreads();

        // ---- wave 0: gather + coherent h store -> drain -> done-flag ----
        if (tid < 32) {
            union { uint4 v; unsigned long long u[2]; } cv;
            cv.v = *reinterpret_cast<const uint4*>(&hlds[tid][0]);
            const int m = 32 * hf + tid;
            unsigned long long* dst = reinterpret_cast<unsigned long long*>(
                hout + (((size_t)(m >> 4) * 32 + (g >> 2)) * 64 + (g & 3) * 16 + (m & 15)) * 8);
            __hip_atomic_store(dst,     cv.u[0], __ATOMIC_RELAXED, __HIP_MEMORY_SCOPE_AGENT);
            __hip_atomic_store(dst + 1, cv.u[1], __ATOMIC_RELAXED, __HIP_MEMORY_SCOPE_AGENT);
        }
        if (w == 0)
            asm volatile("s_waitcnt vmcnt(0)" ::: "memory");   // wave-0 stores only
        if (tid == 0)
            __hip_atomic_store(&flags[g * 16], (unsigned)(t + 1),
                               __ATOMIC_RELAXED, __HIP_MEMORY_SCOPE_AGENT);

        // ---- off-critical-path tail ----
        // wave 1: h1A history store (HBM ack never gates the done-flag drain)
        if (h1A && tid >= 64 && tid < 96) {
            const int r = tid - 64;
            union { uint4 v; unsigned long long u[2]; } cv;
            cv.v = *reinterpret_cast<const uint4*>(&hlds[r][0]);
            const int m = 32 * hf + r;
            const size_t mg = (size_t)t * 64 + m;   // packed-A row r = t*64 + m
            *reinterpret_cast<uint4*>(
                h1A + (((mg >> 4) * 32 + (size_t)(g >> 2)) * 64 + (g & 3) * 16 + (mg & 15)) * 8) = cv.v;
        }
        // waves 0,1 (kh==0): next-step x4s prefetch (consumed after barrier)
        if (kh == 0 && t + 1 < SS) {
            xv0 = *reinterpret_cast<const ushort4*>(
                x4s + ((size_t)(t + 1) * GG + gq0) * 64 + 32 * hf + rbase);
            xv1 = *reinterpret_cast<const ushort4*>(
                x4s + ((size_t)(t + 1) * GG + gq1) * 64 + 32 * hf + rbase);
        }

        // ---- 2-hop barrier: leader wave observes 128 flags, publishes go ----
        if (g == 0) {
            if (tid < 64) {
                const unsigned tgt = (unsigned)(t + 1);
                unsigned v0 = 0, v1 = 0;
                while (1) {
                    if (v0 < tgt)
                        v0 = __hip_atomic_load(&flags[tid * 16], __ATOMIC_RELAXED,
                                               __HIP_MEMORY_SCOPE_AGENT);
                    if (v1 < tgt)
                        v1 = __hip_atomic_load(&flags[(tid + 64) * 16], __ATOMIC_RELAXED,
                                               __HIP_MEMORY_SCOPE_AGENT);
                    if (__all((v0 >= tgt) && (v1 >= tgt))) break;
                    __builtin_amdgcn_s_sleep(1);
                }
                if (tid == 0)
                    __hip_atomic_store(gof, tgt, __ATOMIC_RELAXED,
                                       __HIP_MEMORY_SCOPE_AGENT);
            }
            __syncthreads();
        } else {
            if (tid == 0) {
                while (__hip_atomic_load(gof, __ATOMIC_RELAXED,
                                         __HIP_MEMORY_SCOPE_AGENT) < (unsigned)(t + 1))
                    __builtin_amdgcn_s_sleep(1);
            }
            __syncthreads();
        }
    }
}

__global__ __launch_bounds__(256) void softmax_rows(const float* __restrict__ logits,
                                                    float* __restrict__ out) {
    __shared__ float red[256];
    int rr = blockIdx.x, tid = threadIdx.x;
    const float* L = logits + (size_t)rr * VV;
    float m = -1e30f;
    for (int i = tid; i < VV; i += 256) m = fmaxf(m, L[i]);
    red[tid] = m; __syncthreads();
    for (int s = 128; s > 0; s >>= 1) { if (tid < s) red[tid] = fmaxf(red[tid], red[tid + s]); __syncthreads(); }
    m = red[0]; __syncthreads();
    float sum = 0.f;
    for (int i = tid; i < VV; i += 256) sum += expf(L[i] - m);
    red[tid] = sum; __syncthreads();
    for (int s = 128; s > 0; s >>= 1) { if (tid < s) red[tid] += red[tid + s]; __syncthreads(); }
    float inv = 1.f / red[0];
    for (int i = tid; i < VV; i += 256) out[(size_t)rr * VV + i] = expf(L[i] - m) * inv;
}

extern "C" void kernel_launch(void* const* d_in, const int* in_sizes, int n_in,
                              void* d_out, int out_size, void* d_ws, size_t ws_size,
                              hipStream_t stream) {
    const int*   x    = (const int*)  d_in[0];
    const float* tab  = (const float*)d_in[1];
    const float* Wx0  = (const float*)d_in[2];
    const float* Wh0  = (const float*)d_in[3];
    const float* b0   = (const float*)d_in[4];
    const float* Wx1  = (const float*)d_in[5];
    const float* Wh1  = (const float*)d_in[6];
    const float* b1   = (const float*)d_in[7];
    const float* Wout = (const float*)d_in[8];
    const float* bout = (const float*)d_in[9];
    float* out = (float*)d_out;

    // ---- workspace layout (ushort units); all segments 16B-aligned ----
    unsigned short* ws    = (unsigned short*)d_ws;
    unsigned short* embA  = ws;                    // 16,777,216
    unsigned short* wx0p  = embA  + 16777216;      //  2,097,152
    unsigned short* wh0p  = wx0p  + 2097152;       //  4,194,304
    unsigned short* wx1p  = wh0p  + 4194304;       //  4,194,304
    unsigned short* wh1p  = wx1p  + 4194304;       //  4,194,304
    unsigned short* woutp = wh1p  + 4194304;       // 32,768,000
    unsigned short* x4s   = woutp + 32768000;      // 134,217,728 (reused by both layers)
    unsigned short* h1A   = x4s   + 134217728;     // 33,554,432
    unsigned short* hb0   = h1A   + 33554432;      // 65,536  (layer 0)
    unsigned short* hb1   = hb0   + 65536;         // 65,536
    unsigned short* hb2   = hb1   + 65536;         // 65,536  (layer 1)
    unsigned short* hb3   = hb2   + 65536;         // 65,536
    float* logits = (float*)(hb3 + 65536);         // 2,048,000 f32
    unsigned int* flags = (unsigned int*)(logits + 2048000);  // 8192 done + 64 go
    // total ~472 MB

    // ---- weight packing ----
    pack_b <<<256 * 16, 64, 0, stream>>>(Wx0, wx0p, 16, GG);
    pack_wh<<<8192, 64, 0, stream>>>(Wh0, wh0p);
    pack_b <<<256 * 32, 64, 0, stream>>>(Wx1, wx1p, 32, GG);
    pack_wh<<<8192, 64, 0, stream>>>(Wh1, wh1p);
    pack_b <<<2000 * 32, 64, 0, stream>>>(Wout, woutp, 32, VV);

    // ---- h0 + flag init ----
    zero_init<<<64, 256, 0, stream>>>(hb0, hb2, flags);

    // ---- embedding + layer-0 input projection ----
    embed_pack<<<32768, 64, 0, stream>>>(x, tab, embA);
    gemm_bias<1><<<dim3(GG / 64, 32768 / 64), 256, 0, stream>>>(embA, wx0p, b0, x4s, GG, EE / 32);

    // ---- layer 0 recurrence (persistent cooperative) ----
    {
        const unsigned short* a0 = x4s; const unsigned short* a1 = wh0p;
        unsigned short *a2 = hb0, *a3 = hb1, *a4 = h1A;
        unsigned int* a5 = flags;
        unsigned int* a6 = flags + 8192;
        void* args[] = {&a0, &a1, &a2, &a3, &a4, &a5, &a6};
        hipLaunchCooperativeKernel((const void*)lstm_layer, dim3(256), dim3(256),
                                   args, 0, stream);
    }

    // ---- layer-1 input projection + recurrence ----
    gemm_bias<1><<<dim3(GG / 64, 32768 / 64), 256, 0, stream>>>(h1A, wx1p, b1, x4s, GG, HH / 32);
    {
        const unsigned short* a0 = x4s; const unsigned short* a1 = wh1p;
        unsigned short *a2 = hb2, *a3 = hb3, *a4 = nullptr;
        unsigned int* a5 = flags + 4096;
        unsigned int* a6 = flags + 8192 + 32;
        void* args[] = {&a0, &a1, &a2, &a3, &a4, &a5, &a6};
        hipLaunchCooperativeKernel((const void*)lstm_layer, dim3(256), dim3(256),
                                   args, 0, stream);
    }
    // t=511 (odd) writes hb2

    // ---- logits (last timestep) + softmax ----
    gemm_bias<0><<<dim3(VV / 64, 1), 256, 0, stream>>>(hb2, woutp, bout, logits, VV, HH / 32);
    softmax_rows<<<64, 256, 0, stream>>>(logits, out);
}

// Round 6
// 4629.546 us; speedup vs baseline: 1.4704x; 1.2295x over previous
//
#include <hip/hip_runtime.h>

// ---------------------------------------------------------------------------
// LanguageModel: embed -> LSTM(1024) x2 -> last-step logits(32000) -> softmax
// B=64, S=512, E=512, H=1024, G=4H=4096, V=32000
//
// Round 10 (fused two-layer pipeline):
//  - Rounds 7-9 showed the per-step barrier chain (~4us) is the floor of the
//    single-layer structure. Instead of shaving it, stop paying it twice:
//    ONE cooperative kernel, 512 blocks @ 2/CU. Blocks 0-255 = layer 0
//    (round-9 body verbatim); blocks 256-511 = layer 1, lagging 1 step.
//  - Layer 1 computes its x-projection ON THE FLY: h1(t)@Wx1_slice fused into
//    the same accumulators as the h2@Wh1 recurrent GEMM (Wx1 packed via
//    pack_wh; 64KB/block slice streamed from L2). Mid-GEMM, h1A history
//    array, and layer-1 x4s traffic all eliminated; b1 added as constants.
//  - Blds was 2x over-allocated (only 64KB indexed); trimmed -> 75KB LDS ->
//    2 blocks/CU. __launch_bounds__(256,2) caps VGPR at 256.
//  - Sync DAG: L0(t) waits L0go>=t, L1go>=t-1 (overwrite protection, 2-step
//    slack). L1(t) waits L1go>=t, L0go>=t+1. L1 runs its recurrent MFMAs
//    BEFORE polling L0go, hiding the cross-layer wait under compute.
// ---------------------------------------------------------------------------

#define BB 64
#define SS 512
#define EE 512
#define HH 1024
#define GG 4096
#define VV 32000

using bf16x8 = __attribute__((ext_vector_type(8))) __bf16;
using f32x4  = __attribute__((ext_vector_type(4))) float;

__device__ __forceinline__ unsigned short f2bf(float f) {
    unsigned u = __float_as_uint(f);
    unsigned r = u + 0x7FFFu + ((u >> 16) & 1u);   // RNE
    return (unsigned short)(r >> 16);
}
__device__ __forceinline__ float bf2f(unsigned short u) {
    return __uint_as_float(((unsigned)u) << 16);
}
__device__ __forceinline__ float sigm(float x) {
    return 1.0f / (1.0f + expf(-x));
}
// 16B fragment load via two agent-scope relaxed atomics (sc1 -> coherent at IF).
__device__ __forceinline__ bf16x8 ld_frag_coh(const unsigned long long* p) {
    union { unsigned long long u[2]; bf16x8 v; } x;
    x.u[0] = __hip_atomic_load(p,     __ATOMIC_RELAXED, __HIP_MEMORY_SCOPE_AGENT);
    x.u[1] = __hip_atomic_load(p + 1, __ATOMIC_RELAXED, __HIP_MEMORY_SCOPE_AGENT);
    return x.v;
}

// Packed-B layout: elem(nt, kt, lane, j) = B[kt*32 + (lane>>4)*8 + j][nt*16 + (lane&15)]
__global__ void pack_b(const float* __restrict__ B, unsigned short* __restrict__ out,
                       int KT, int N) {
    int bid = blockIdx.x;          // = nt*KT + kt
    int lane = threadIdx.x;
    int nt = bid / KT, kt = bid % KT;
    int k = kt * 32 + ((lane >> 4) << 3);
    int n = nt * 16 + (lane & 15);
    size_t base = ((size_t)bid * 64 + lane) * 8;
    #pragma unroll
    for (int j = 0; j < 8; ++j)
        out[base + j] = f2bf(B[(size_t)(k + j) * N + n]);
}

// Wh pack: colgroup g in [0,128) owns h-cols 8g..8g+7
// -> 32 gate-cols ordered n = q*8+cj (q=gate, cj=col offset), as 2 n-tiles.
// Frag id f = (g*2 + nt)*32 + kt.  (Also used for Wx1: same 1024x4096 shape.)
__global__ void pack_wh(const float* __restrict__ Wh, unsigned short* __restrict__ out) {
    int f = blockIdx.x;            // (g*2 + nt)*32 + kt ; grid 8192
    int lane = threadIdx.x;
    int kt = f & 31, nt = (f >> 5) & 1, g = f >> 6;
    int nloc = lane & 15;
    int q = nt * 2 + (nloc >> 3), cj = nloc & 7;
    int gcol = q * HH + 8 * g + cj;
    int k = kt * 32 + ((lane >> 4) << 3);
    size_t base = ((size_t)f * 64 + lane) * 8;
    #pragma unroll
    for (int j = 0; j < 8; ++j)
        out[base + j] = f2bf(Wh[(size_t)(k + j) * GG + gcol]);
}

// Embedding gather written directly in packed-A form (M=32768 rows, K=512).
// Row order r = s*64 + b  (s-major, batch innermost).
__global__ void embed_pack(const int* __restrict__ x, const float* __restrict__ tab,
                           unsigned short* __restrict__ out) {
    int bid = blockIdx.x;          // = mt*16 + kt  (KT=16)
    int lane = threadIdx.x;
    int mt = bid >> 4, kt = bid & 15;
    int m = mt * 16 + (lane & 15);            // r = s*64 + b
    int idx = x[(m & 63) * SS + (m >> 6)];    // x is [B][S]
    int kb = kt * 32 + ((lane >> 4) << 3);
    size_t base = ((size_t)bid * 64 + lane) * 8;
    const float* src = tab + (size_t)idx * EE + kb;
    #pragma unroll
    for (int j = 0; j < 8; ++j)
        out[base + j] = f2bf(src[j]);
}

// C = A@B + bias.  MODE 0: float row-major (logits).
//                  MODE 1: bf16 x4s layout out[((s*GG + col)*64 + batch)],
//                          virtual row r = s*64 + batch; block owns one s x
//                          64 cols x 64 batches = contiguous 8KB region.
template<int MODE>
__global__ __launch_bounds__(256) void gemm_bias(
    const unsigned short* __restrict__ Ap, const unsigned short* __restrict__ Bp,
    const float* __restrict__ bias, void* __restrict__ Cout, int N, int KT) {
    __shared__ unsigned short tile[64][72];   // MODE1 transpose staging (padded)
    const int tid = threadIdx.x, lane = tid & 63, w = tid >> 6;
    const int ntg = blockIdx.x * 4 + w;
    const int m0t = blockIdx.y * 4;
    const bf16x8* Av = reinterpret_cast<const bf16x8*>(Ap);
    const bf16x8* Bv = reinterpret_cast<const bf16x8*>(Bp);
    f32x4 acc[4] = {{0.f,0.f,0.f,0.f},{0.f,0.f,0.f,0.f},{0.f,0.f,0.f,0.f},{0.f,0.f,0.f,0.f}};
    for (int kt = 0; kt < KT; ++kt) {
        bf16x8 b = Bv[((size_t)ntg * KT + kt) * 64 + lane];
        #pragma unroll
        for (int mt = 0; mt < 4; ++mt) {
            bf16x8 a = Av[((size_t)(m0t + mt) * KT + kt) * 64 + lane];
            acc[mt] = __builtin_amdgcn_mfma_f32_16x16x32_bf16(a, b, acc[mt], 0, 0, 0);
        }
    }
    const int col = ntg * 16 + (lane & 15);
    const int rq = (lane >> 4) << 2;
    const float bb = bias[col];
    if (MODE == 0) {
        #pragma unroll
        for (int mt = 0; mt < 4; ++mt)
            #pragma unroll
            for (int i = 0; i < 4; ++i) {
                int row = (m0t + mt) * 16 + rq + i;
                ((float*)Cout)[(size_t)row * N + col] = acc[mt][i] + bb;
            }
    } else {
        const int cl = w * 16 + (lane & 15);            // block-local col
        #pragma unroll
        for (int mt = 0; mt < 4; ++mt)
            #pragma unroll
            for (int i = 0; i < 4; ++i)
                tile[cl][mt * 16 + rq + i] = f2bf(acc[mt][i] + bb);
        __syncthreads();
        // linear 8KB store: out element (s*GG + col0)*64 + c*64 + b
        const int c = tid >> 2, b0 = (tid & 3) << 4;
        unsigned short* dst = (unsigned short*)Cout +
            ((size_t)blockIdx.y * GG + (size_t)blockIdx.x * 64) * 64 + (size_t)tid * 16;
        const uint4* s4 = reinterpret_cast<const uint4*>(&tile[c][b0]);
        reinterpret_cast<uint4*>(dst)[0] = s4[0];
        reinterpret_cast<uint4*>(dst)[1] = s4[1];
    }
}

// Zero h0 for both layers + all barrier flags (incl. go-flags at [8192,8256)).
__global__ void zero_init(unsigned short* __restrict__ h0a,
                          unsigned short* __restrict__ h0b,
                          unsigned int* __restrict__ flags) {
    int i = blockIdx.x * 256 + threadIdx.x;      // grid 64 x 256
    for (int k = i; k < BB * HH; k += 64 * 256) { h0a[k] = 0; h0b[k] = 0; }
    for (int k = i; k < 8256; k += 64 * 256) flags[k] = 0;
}

// Fused two-layer persistent LSTM. Grid 512 x 256 (cooperative, 2 blocks/CU).
// Block b: L = b>=256, inner = b&255, g = inner>>1 (h-colgroup), hf = inner&1.
// Flags: done[L][hf][128] (16-u32 padded lines), go[L][hf] at +8192.
// Go-flag value v  <=>  that layer+domain has completed steps 0..v-1.
__global__ __launch_bounds__(256, 2) void lstm_fused(
    const unsigned short* __restrict__ x4s,   // layer-0 input proj (s-major x4)
    const unsigned short* __restrict__ wh0p, const unsigned short* __restrict__ wh1p,
    const unsigned short* __restrict__ wx1p,  // pack_wh layout
    const float* __restrict__ b1,
    unsigned short* __restrict__ hb0, unsigned short* __restrict__ hb1,
    unsigned short* __restrict__ hb2, unsigned short* __restrict__ hb3,
    unsigned int* __restrict__ flags) {
    __shared__ float gx[2][32][36];                         // [khalf][n][block-row]
    __shared__ __align__(16) unsigned short hlds[32][8];    // gathered h chunks
    __shared__ __align__(16) unsigned short Blds[64 * 64 * 8];  // 64 KB Wh slice
    const int tid = threadIdx.x, lane = tid & 63, w = tid >> 6;
    const int L = (blockIdx.x >= 256) ? 1 : 0;
    const int inner = blockIdx.x & 255;
    const int g = inner >> 1, hf = inner & 1;
    unsigned int* done    = flags + L * 4096 + hf * 2048;           // 128 x 16
    unsigned int* gof_own = flags + 8192 + L * 32 + hf * 16;
    unsigned int* gof_oth = flags + 8192 + (1 - L) * 32 + hf * 16;

    // ---- stage this colgroup's Wh slice (64 KB) into LDS, once ----
    {
        const uint4* src = reinterpret_cast<const uint4*>(L ? wh1p : wh0p) + (size_t)g * 4096;
        uint4* dst = reinterpret_cast<uint4*>(Blds);
        #pragma unroll
        for (int i = 0; i < 16; ++i)
            dst[i * 256 + tid] = src[i * 256 + tid];
    }
    __syncthreads();
    const bf16x8* Bl = reinterpret_cast<const bf16x8*>(Blds);
    const bf16x8* Wx = reinterpret_cast<const bf16x8*>(wx1p);

    const int msub = w & 1, kh = w >> 1;
    const int kh16 = kh * 16;
    const int nloc = lane & 15;
    const int cj = nloc & 7;
    const int q0 = nloc >> 3;                               // gate idx for nt=0
    const int gq0 = q0 * HH + 8 * g + cj;                   // nt=0 gate col
    const int gq1 = (2 + q0) * HH + 8 * g + cj;             // nt=1 gate col
    const int rbase = msub * 16 + ((lane >> 4) << 2);       // block-local row base
    const size_t afrag_base = ((size_t)(2 * hf + msub) * 32 + (size_t)kh * 16) * 64 + lane;
    const int row_l = tid >> 3, cj2 = tid & 7;
    float c = 0.f;

    if (L == 0) {
        // =================== layer 0 (round-9 proven body) ===================
        ushort4 xv0 = {0, 0, 0, 0}, xv1 = {0, 0, 0, 0};
        if (kh == 0) {
            xv0 = *reinterpret_cast<const ushort4*>(x4s + ((size_t)gq0) * 64 + 32 * hf + rbase);
            xv1 = *reinterpret_cast<const ushort4*>(x4s + ((size_t)gq1) * 64 + 32 * hf + rbase);
        }
        #pragma unroll 1
        for (int t = 0; t < SS; ++t) {
            // entry gates: own domain done t-1; L1 done t-2 (buffer overwrite guard)
            if (t > 0) {
                if (tid == 0) {
                    while (__hip_atomic_load(gof_own, __ATOMIC_RELAXED,
                                             __HIP_MEMORY_SCOPE_AGENT) < (unsigned)t)
                        __builtin_amdgcn_s_sleep(1);
                    if (t >= 2)
                        while (__hip_atomic_load(gof_oth, __ATOMIC_RELAXED,
                                                 __HIP_MEMORY_SCOPE_AGENT) < (unsigned)(t - 1))
                            __builtin_amdgcn_s_sleep(1);
                }
                __syncthreads();
            }
            const unsigned long long* hv =
                reinterpret_cast<const unsigned long long*>((t & 1) ? hb1 : hb0);
            unsigned short* hout = (t & 1) ? hb0 : hb1;

            bf16x8 A[16];
            #pragma unroll
            for (int k = 0; k < 16; ++k)
                A[k] = ld_frag_coh(hv + (afrag_base + (size_t)k * 64) * 2);

            f32x4 acc0 = {0.f, 0.f, 0.f, 0.f}, acc1 = {0.f, 0.f, 0.f, 0.f};
            #pragma unroll
            for (int k = 0; k < 16; ++k) {
                acc0 = __builtin_amdgcn_mfma_f32_16x16x32_bf16(
                    A[k], Bl[(kh16 + k) * 64 + lane], acc0, 0, 0, 0);
                acc1 = __builtin_amdgcn_mfma_f32_16x16x32_bf16(
                    A[k], Bl[(32 + kh16 + k) * 64 + lane], acc1, 0, 0, 0);
            }
            if (kh == 0) {
                gx[0][nloc][rbase + 0] = acc0[0] + bf2f(xv0.x);
                gx[0][nloc][rbase + 1] = acc0[1] + bf2f(xv0.y);
                gx[0][nloc][rbase + 2] = acc0[2] + bf2f(xv0.z);
                gx[0][nloc][rbase + 3] = acc0[3] + bf2f(xv0.w);
                gx[0][16 + nloc][rbase + 0] = acc1[0] + bf2f(xv1.x);
                gx[0][16 + nloc][rbase + 1] = acc1[1] + bf2f(xv1.y);
                gx[0][16 + nloc][rbase + 2] = acc1[2] + bf2f(xv1.z);
                gx[0][16 + nloc][rbase + 3] = acc1[3] + bf2f(xv1.w);
            } else {
                gx[1][nloc][rbase + 0] = acc0[0];
                gx[1][nloc][rbase + 1] = acc0[1];
                gx[1][nloc][rbase + 2] = acc0[2];
                gx[1][nloc][rbase + 3] = acc0[3];
                gx[1][16 + nloc][rbase + 0] = acc1[0];
                gx[1][16 + nloc][rbase + 1] = acc1[1];
                gx[1][16 + nloc][rbase + 2] = acc1[2];
                gx[1][16 + nloc][rbase + 3] = acc1[3];
            }
            __syncthreads();

            float gi = gx[0][0 * 8 + cj2][row_l] + gx[1][0 * 8 + cj2][row_l];
            float gf = gx[0][1 * 8 + cj2][row_l] + gx[1][1 * 8 + cj2][row_l];
            float gg = gx[0][2 * 8 + cj2][row_l] + gx[1][2 * 8 + cj2][row_l];
            float go = gx[0][3 * 8 + cj2][row_l] + gx[1][3 * 8 + cj2][row_l];
            float cn = sigm(gf) * c + sigm(gi) * tanhf(gg);
            c = cn;
            hlds[row_l][cj2] = f2bf(sigm(go) * tanhf(cn));
            __syncthreads();

            if (tid < 32) {
                union { uint4 v; unsigned long long u[2]; } cv;
                cv.v = *reinterpret_cast<const uint4*>(&hlds[tid][0]);
                const int m = 32 * hf + tid;
                unsigned long long* dst = reinterpret_cast<unsigned long long*>(
                    hout + (((size_t)(m >> 4) * 32 + (g >> 2)) * 64 + (g & 3) * 16 + (m & 15)) * 8);
                __hip_atomic_store(dst,     cv.u[0], __ATOMIC_RELAXED, __HIP_MEMORY_SCOPE_AGENT);
                __hip_atomic_store(dst + 1, cv.u[1], __ATOMIC_RELAXED, __HIP_MEMORY_SCOPE_AGENT);
            }
            if (w == 0)
                asm volatile("s_waitcnt vmcnt(0)" ::: "memory");   // wave-0 stores only
            if (tid == 0)
                __hip_atomic_store(&done[g * 16], (unsigned)(t + 1),
                                   __ATOMIC_RELAXED, __HIP_MEMORY_SCOPE_AGENT);
            // off-path: next-step xv prefetch
            if (kh == 0 && t + 1 < SS) {
                xv0 = *reinterpret_cast<const ushort4*>(
                    x4s + ((size_t)(t + 1) * GG + gq0) * 64 + 32 * hf + rbase);
                xv1 = *reinterpret_cast<const ushort4*>(
                    x4s + ((size_t)(t + 1) * GG + gq1) * 64 + 32 * hf + rbase);
            }
            // leader: observe 128 done-flags, publish go
            if (g == 0 && tid < 64) {
                const unsigned tgt = (unsigned)(t + 1);
                unsigned v0 = 0, v1 = 0;
                while (1) {
                    if (v0 < tgt)
                        v0 = __hip_atomic_load(&done[tid * 16], __ATOMIC_RELAXED,
                                               __HIP_MEMORY_SCOPE_AGENT);
                    if (v1 < tgt)
                        v1 = __hip_atomic_load(&done[(tid + 64) * 16], __ATOMIC_RELAXED,
                                               __HIP_MEMORY_SCOPE_AGENT);
                    if (__all((v0 >= tgt) && (v1 >= tgt))) break;
                    __builtin_amdgcn_s_sleep(1);
                }
                if (tid == 0)
                    __hip_atomic_store(gof_own, tgt, __ATOMIC_RELAXED,
                                       __HIP_MEMORY_SCOPE_AGENT);
            }
        }
    } else {
        // =================== layer 1 (lag 1; fused x-projection) =============
        const float bb0 = b1[gq0], bb1 = b1[gq1];
        #pragma unroll 1
        for (int t = 0; t < SS; ++t) {
            // entry gate: own domain done t-1
            if (t > 0) {
                if (tid == 0) {
                    while (__hip_atomic_load(gof_own, __ATOMIC_RELAXED,
                                             __HIP_MEMORY_SCOPE_AGENT) < (unsigned)t)
                        __builtin_amdgcn_s_sleep(1);
                }
                __syncthreads();
            }
            const unsigned long long* hv2 =
                reinterpret_cast<const unsigned long long*>((t & 1) ? hb3 : hb2);
            unsigned short* hout2 = (t & 1) ? hb2 : hb3;

            // own-state fragments + recurrent GEMM (independent of layer 0)
            bf16x8 A2[16];
            #pragma unroll
            for (int k = 0; k < 16; ++k)
                A2[k] = ld_frag_coh(hv2 + (afrag_base + (size_t)k * 64) * 2);

            f32x4 acc0 = {0.f, 0.f, 0.f, 0.f}, acc1 = {0.f, 0.f, 0.f, 0.f};
            #pragma unroll
            for (int k = 0; k < 16; ++k) {
                acc0 = __builtin_amdgcn_mfma_f32_16x16x32_bf16(
                    A2[k], Bl[(kh16 + k) * 64 + lane], acc0, 0, 0, 0);
                acc1 = __builtin_amdgcn_mfma_f32_16x16x32_bf16(
                    A2[k], Bl[(32 + kh16 + k) * 64 + lane], acc1, 0, 0, 0);
            }

            // cross-layer gate: h1(t) published by layer 0
            if (tid == 0) {
                while (__hip_atomic_load(gof_oth, __ATOMIC_RELAXED,
                                         __HIP_MEMORY_SCOPE_AGENT) < (unsigned)(t + 1))
                    __builtin_amdgcn_s_sleep(1);
            }
            __syncthreads();

            // h1(t) fragments + on-the-fly x-projection (B from L2-resident Wx1)
            const unsigned long long* hv1 =
                reinterpret_cast<const unsigned long long*>((t & 1) ? hb0 : hb1);
            bf16x8 A1[16];
            #pragma unroll
            for (int k = 0; k < 16; ++k)
                A1[k] = ld_frag_coh(hv1 + (afrag_base + (size_t)k * 64) * 2);

            bf16x8 BXa[8], BXb[8];
            #pragma unroll
            for (int j = 0; j < 8; ++j) {
                BXa[j] = Wx[((size_t)(g * 64 + kh16 + j)) * 64 + lane];
                BXb[j] = Wx[((size_t)(g * 64 + 32 + kh16 + j)) * 64 + lane];
            }
            #pragma unroll
            for (int j = 0; j < 8; ++j) {
                acc0 = __builtin_amdgcn_mfma_f32_16x16x32_bf16(A1[j], BXa[j], acc0, 0, 0, 0);
                acc1 = __builtin_amdgcn_mfma_f32_16x16x32_bf16(A1[j], BXb[j], acc1, 0, 0, 0);
            }
            #pragma unroll
            for (int j = 0; j < 8; ++j) {
                BXa[j] = Wx[((size_t)(g * 64 + kh16 + 8 + j)) * 64 + lane];
                BXb[j] = Wx[((size_t)(g * 64 + 32 + kh16 + 8 + j)) * 64 + lane];
            }
            #pragma unroll
            for (int j = 0; j < 8; ++j) {
                acc0 = __builtin_amdgcn_mfma_f32_16x16x32_bf16(A1[8 + j], BXa[j], acc0, 0, 0, 0);
                acc1 = __builtin_amdgcn_mfma_f32_16x16x32_bf16(A1[8 + j], BXb[j], acc1, 0, 0, 0);
            }

            if (kh == 0) {
                gx[0][nloc][rbase + 0] = acc0[0] + bb0;
                gx[0][nloc][rbase + 1] = acc0[1] + bb0;
                gx[0][nloc][rbase + 2] = acc0[2] + bb0;
                gx[0][nloc][rbase + 3] = acc0[3] + bb0;
                gx[0][16 + nloc][rbase + 0] = acc1[0] + bb1;
                gx[0][16 + nloc][rbase + 1] = acc1[1] + bb1;
                gx[0][16 + nloc][rbase + 2] = acc1[2] + bb1;
                gx[0][16 + nloc][rbase + 3] = acc1[3] + bb1;
            } else {
                gx[1][nloc][rbase + 0] = acc0[0];
                gx[1][nloc][rbase + 1] = acc0[1];
                gx[1][nloc][rbase + 2] = acc0[2];
                gx[1][nloc][rbase + 3] = acc0[3];
                gx[1][16 + nloc][rbase + 0] = acc1[0];
                gx[1][16 + nloc][rbase + 1] = acc1[1];
                gx[1][16 + nloc][rbase + 2] = acc1[2];
                gx[1][16 + nloc][rbase + 3] = acc1[3];
            }
            __syncthreads();

            float gi = gx[0][0 * 8 + cj2][row_l] + gx[1][0 * 8 + cj2][row_l];
            float gf = gx[0][1 * 8 + cj2][row_l] + gx[1][1 * 8 + cj2][row_l];
            float gg = gx[0][2 * 8 + cj2][row_l] + gx[1][2 * 8 + cj2][row_l];
            float go = gx[0][3 * 8 + cj2][row_l] + gx[1][3 * 8 + cj2][row_l];
            float cn = sigm(gf) * c + sigm(gi) * tanhf(gg);
            c = cn;
            hlds[row_l][cj2] = f2bf(sigm(go) * tanhf(cn));
            __syncthreads();

            if (tid < 32) {
                union { uint4 v; unsigned long long u[2]; } cv;
                cv.v = *reinterpret_cast<const uint4*>(&hlds[tid][0]);
                const int m = 32 * hf + tid;
                unsigned long long* dst = reinterpret_cast<unsigned long long*>(
                    hout2 + (((size_t)(m >> 4) * 32 + (g >> 2)) * 64 + (g & 3) * 16 + (m & 15)) * 8);
                __hip_atomic_store(dst,     cv.u[0], __ATOMIC_RELAXED, __HIP_MEMORY_SCOPE_AGENT);
                __hip_atomic_store(dst + 1, cv.u[1], __ATOMIC_RELAXED, __HIP_MEMORY_SCOPE_AGENT);
            }
            if (w == 0)
                asm volatile("s_waitcnt vmcnt(0)" ::: "memory");
            if (tid == 0)
                __hip_atomic_store(&done[g * 16], (unsigned)(t + 1),
                                   __ATOMIC_RELAXED, __HIP_MEMORY_SCOPE_AGENT);
            if (g == 0 && tid < 64) {
                const unsigned tgt = (unsigned)(t + 1);
                unsigned v0 = 0, v1 = 0;
                while (1) {
                    if (v0 < tgt)
                        v0 = __hip_atomic_load(&done[tid * 16], __ATOMIC_RELAXED,
                                               __HIP_MEMORY_SCOPE_AGENT);
                    if (v1 < tgt)
                        v1 = __hip_atomic_load(&done[(tid + 64) * 16], __ATOMIC_RELAXED,
                                               __HIP_MEMORY_SCOPE_AGENT);
                    if (__all((v0 >= tgt) && (v1 >= tgt))) break;
                    __builtin_amdgcn_s_sleep(1);
                }
                if (tid == 0)
                    __hip_atomic_store(gof_own, tgt, __ATOMIC_RELAXED,
                                       __HIP_MEMORY_SCOPE_AGENT);
            }
        }
    }
}

__global__ __launch_bounds__(256) void softmax_rows(const float* __restrict__ logits,
                                                    float* __restrict__ out) {
    __shared__ float red[256];
    int rr = blockIdx.x, tid = threadIdx.x;
    const float* L = logits + (size_t)rr * VV;
    float m = -1e30f;
    for (int i = tid; i < VV; i += 256) m = fmaxf(m, L[i]);
    red[tid] = m; __syncthreads();
    for (int s = 128; s > 0; s >>= 1) { if (tid < s) red[tid] = fmaxf(red[tid], red[tid + s]); __syncthreads(); }
    m = red[0]; __syncthreads();
    float sum = 0.f;
    for (int i = tid; i < VV; i += 256) sum += expf(L[i] - m);
    red[tid] = sum; __syncthreads();
    for (int s = 128; s > 0; s >>= 1) { if (tid < s) red[tid] += red[tid + s]; __syncthreads(); }
    float inv = 1.f / red[0];
    for (int i = tid; i < VV; i += 256) out[(size_t)rr * VV + i] = expf(L[i] - m) * inv;
}

extern "C" void kernel_launch(void* const* d_in, const int* in_sizes, int n_in,
                              void* d_out, int out_size, void* d_ws, size_t ws_size,
                              hipStream_t stream) {
    const int*   x    = (const int*)  d_in[0];
    const float* tab  = (const float*)d_in[1];
    const float* Wx0  = (const float*)d_in[2];
    const float* Wh0  = (const float*)d_in[3];
    const float* b0   = (const float*)d_in[4];
    const float* Wx1  = (const float*)d_in[5];
    const float* Wh1  = (const float*)d_in[6];
    const float* b1   = (const float*)d_in[7];
    const float* Wout = (const float*)d_in[8];
    const float* bout = (const float*)d_in[9];
    float* out = (float*)d_out;

    // ---- workspace layout (ushort units); all segments 16B-aligned ----
    unsigned short* ws    = (unsigned short*)d_ws;
    unsigned short* embA  = ws;                    // 16,777,216
    unsigned short* wx0p  = embA  + 16777216;      //  2,097,152
    unsigned short* wh0p  = wx0p  + 2097152;       //  4,194,304
    unsigned short* wx1p  = wh0p  + 4194304;       //  4,194,304 (pack_wh layout)
    unsigned short* wh1p  = wx1p  + 4194304;       //  4,194,304
    unsigned short* woutp = wh1p  + 4194304;       // 32,768,000
    unsigned short* x4s   = woutp + 32768000;      // 134,217,728 (layer-0 only)
    unsigned short* h1A   = x4s   + 134217728;     // 33,554,432 (unused now)
    unsigned short* hb0   = h1A   + 33554432;      // 65,536  (layer 0)
    unsigned short* hb1   = hb0   + 65536;         // 65,536
    unsigned short* hb2   = hb1   + 65536;         // 65,536  (layer 1)
    unsigned short* hb3   = hb2   + 65536;         // 65,536
    float* logits = (float*)(hb3 + 65536);         // 2,048,000 f32
    unsigned int* flags = (unsigned int*)(logits + 2048000);  // 8192 done + 64 go
    // total ~472 MB

    // ---- weight packing ----
    pack_b <<<256 * 16, 64, 0, stream>>>(Wx0, wx0p, 16, GG);
    pack_wh<<<8192, 64, 0, stream>>>(Wh0, wh0p);
    pack_wh<<<8192, 64, 0, stream>>>(Wx1, wx1p);   // per-colgroup slice layout
    pack_wh<<<8192, 64, 0, stream>>>(Wh1, wh1p);
    pack_b <<<2000 * 32, 64, 0, stream>>>(Wout, woutp, 32, VV);

    // ---- h0 + flag init ----
    zero_init<<<64, 256, 0, stream>>>(hb0, hb2, flags);

    // ---- embedding + layer-0 input projection ----
    embed_pack<<<32768, 64, 0, stream>>>(x, tab, embA);
    gemm_bias<1><<<dim3(GG / 64, 32768 / 64), 256, 0, stream>>>(embA, wx0p, b0, x4s, GG, EE / 32);

    // ---- fused two-layer recurrence (persistent cooperative, 512 blocks) ----
    {
        const unsigned short* a0 = x4s;
        const unsigned short* a1 = wh0p; const unsigned short* a2 = wh1p;
        const unsigned short* a3 = wx1p; const float* a4 = b1;
        unsigned short *a5 = hb0, *a6 = hb1, *a7 = hb2, *a8 = hb3;
        unsigned int* a9 = flags;
        void* args[] = {&a0, &a1, &a2, &a3, &a4, &a5, &a6, &a7, &a8, &a9};
        hipLaunchCooperativeKernel((const void*)lstm_fused, dim3(512), dim3(256),
                                   args, 0, stream);
    }
    // t=511 (odd) writes layer-1 h into hb2

    // ---- logits (last timestep) + softmax ----
    gemm_bias<0><<<dim3(VV / 64, 1), 256, 0, stream>>>(hb2, woutp, bout, logits, VV, HH / 32);
    softmax_rows<<<64, 256, 0, stream>>>(logits, out);
}

// Round 7
// 3884.812 us; speedup vs baseline: 1.7523x; 1.1917x over previous
//
#include <hip/hip_runtime.h>

// ---------------------------------------------------------------------------
// LanguageModel: embed -> LSTM(1024) x2 -> last-step logits(32000) -> softmax
// B=64, S=512, E=512, H=1024, G=4H=4096, V=32000
//
// Round 11 (decongest + reorder the fused pipeline):
//  - Go-flag REPLICATION x16: round-10 had ~254 blocks polling ONE IF line
//    per go flag (~700 same-line accesses/us -> slice oversubscription, the
//    round-5 poll-storm lesson recurring). Leader lanes 0-15 store 16
//    replica lines; each block polls replica (g&15) -> ~16 pollers/line.
//  - Gates are now ALL-THREAD polls (wave-coalesced, same address) instead of
//    tid0 + __syncthreads: removes the barrier AND its vmcnt(0) drain from
//    the gate path. sched_barrier(0) after each gate (rule #18: hipcc hoists
//    loads past inline waits).
//  - L1 body reorder: cross-gate first (free in steady state), A1 issued
//    immediately (flies during own-gate), then A2, then Wx batch-1 ->
//    x-proj MFMAs (hide A2 window) -> recurrent MFMAs. One latency window.
//  - L0 body unchanged except the gate mechanism.
// ---------------------------------------------------------------------------

#define BB 64
#define SS 512
#define EE 512
#define HH 1024
#define GG 4096
#define VV 32000

using bf16x8 = __attribute__((ext_vector_type(8))) __bf16;
using f32x4  = __attribute__((ext_vector_type(4))) float;

__device__ __forceinline__ unsigned short f2bf(float f) {
    unsigned u = __float_as_uint(f);
    unsigned r = u + 0x7FFFu + ((u >> 16) & 1u);   // RNE
    return (unsigned short)(r >> 16);
}
__device__ __forceinline__ float bf2f(unsigned short u) {
    return __uint_as_float(((unsigned)u) << 16);
}
__device__ __forceinline__ float sigm(float x) {
    return 1.0f / (1.0f + expf(-x));
}
// 16B fragment load via two agent-scope relaxed atomics (sc1 -> coherent at IF).
__device__ __forceinline__ bf16x8 ld_frag_coh(const unsigned long long* p) {
    union { unsigned long long u[2]; bf16x8 v; } x;
    x.u[0] = __hip_atomic_load(p,     __ATOMIC_RELAXED, __HIP_MEMORY_SCOPE_AGENT);
    x.u[1] = __hip_atomic_load(p + 1, __ATOMIC_RELAXED, __HIP_MEMORY_SCOPE_AGENT);
    return x.v;
}
// All-thread gate poll on a replicated go line (wave-coalesced same-address).
__device__ __forceinline__ void gate_poll(const unsigned int* p, unsigned tgt) {
    while (__hip_atomic_load(p, __ATOMIC_RELAXED, __HIP_MEMORY_SCOPE_AGENT) < tgt)
        __builtin_amdgcn_s_sleep(1);
    __builtin_amdgcn_sched_barrier(0);   // fence: no load issue hoisted above gate
}

// Packed-B layout: elem(nt, kt, lane, j) = B[kt*32 + (lane>>4)*8 + j][nt*16 + (lane&15)]
__global__ void pack_b(const float* __restrict__ B, unsigned short* __restrict__ out,
                       int KT, int N) {
    int bid = blockIdx.x;          // = nt*KT + kt
    int lane = threadIdx.x;
    int nt = bid / KT, kt = bid % KT;
    int k = kt * 32 + ((lane >> 4) << 3);
    int n = nt * 16 + (lane & 15);
    size_t base = ((size_t)bid * 64 + lane) * 8;
    #pragma unroll
    for (int j = 0; j < 8; ++j)
        out[base + j] = f2bf(B[(size_t)(k + j) * N + n]);
}

// Wh pack: colgroup g in [0,128) owns h-cols 8g..8g+7
// -> 32 gate-cols ordered n = q*8+cj (q=gate, cj=col offset), as 2 n-tiles.
// Frag id f = (g*2 + nt)*32 + kt.  (Also used for Wx1: same 1024x4096 shape.)
__global__ void pack_wh(const float* __restrict__ Wh, unsigned short* __restrict__ out) {
    int f = blockIdx.x;            // (g*2 + nt)*32 + kt ; grid 8192
    int lane = threadIdx.x;
    int kt = f & 31, nt = (f >> 5) & 1, g = f >> 6;
    int nloc = lane & 15;
    int q = nt * 2 + (nloc >> 3), cj = nloc & 7;
    int gcol = q * HH + 8 * g + cj;
    int k = kt * 32 + ((lane >> 4) << 3);
    size_t base = ((size_t)f * 64 + lane) * 8;
    #pragma unroll
    for (int j = 0; j < 8; ++j)
        out[base + j] = f2bf(Wh[(size_t)(k + j) * GG + gcol]);
}

// Embedding gather written directly in packed-A form (M=32768 rows, K=512).
// Row order r = s*64 + b  (s-major, batch innermost).
__global__ void embed_pack(const int* __restrict__ x, const float* __restrict__ tab,
                           unsigned short* __restrict__ out) {
    int bid = blockIdx.x;          // = mt*16 + kt  (KT=16)
    int lane = threadIdx.x;
    int mt = bid >> 4, kt = bid & 15;
    int m = mt * 16 + (lane & 15);            // r = s*64 + b
    int idx = x[(m & 63) * SS + (m >> 6)];    // x is [B][S]
    int kb = kt * 32 + ((lane >> 4) << 3);
    size_t base = ((size_t)bid * 64 + lane) * 8;
    const float* src = tab + (size_t)idx * EE + kb;
    #pragma unroll
    for (int j = 0; j < 8; ++j)
        out[base + j] = f2bf(src[j]);
}

// C = A@B + bias.  MODE 0: float row-major (logits).
//                  MODE 1: bf16 x4s layout out[((s*GG + col)*64 + batch)],
//                          virtual row r = s*64 + batch; block owns one s x
//                          64 cols x 64 batches = contiguous 8KB region.
template<int MODE>
__global__ __launch_bounds__(256) void gemm_bias(
    const unsigned short* __restrict__ Ap, const unsigned short* __restrict__ Bp,
    const float* __restrict__ bias, void* __restrict__ Cout, int N, int KT) {
    __shared__ unsigned short tile[64][72];   // MODE1 transpose staging (padded)
    const int tid = threadIdx.x, lane = tid & 63, w = tid >> 6;
    const int ntg = blockIdx.x * 4 + w;
    const int m0t = blockIdx.y * 4;
    const bf16x8* Av = reinterpret_cast<const bf16x8*>(Ap);
    const bf16x8* Bv = reinterpret_cast<const bf16x8*>(Bp);
    f32x4 acc[4] = {{0.f,0.f,0.f,0.f},{0.f,0.f,0.f,0.f},{0.f,0.f,0.f,0.f},{0.f,0.f,0.f,0.f}};
    for (int kt = 0; kt < KT; ++kt) {
        bf16x8 b = Bv[((size_t)ntg * KT + kt) * 64 + lane];
        #pragma unroll
        for (int mt = 0; mt < 4; ++mt) {
            bf16x8 a = Av[((size_t)(m0t + mt) * KT + kt) * 64 + lane];
            acc[mt] = __builtin_amdgcn_mfma_f32_16x16x32_bf16(a, b, acc[mt], 0, 0, 0);
        }
    }
    const int col = ntg * 16 + (lane & 15);
    const int rq = (lane >> 4) << 2;
    const float bb = bias[col];
    if (MODE == 0) {
        #pragma unroll
        for (int mt = 0; mt < 4; ++mt)
            #pragma unroll
            for (int i = 0; i < 4; ++i) {
                int row = (m0t + mt) * 16 + rq + i;
                ((float*)Cout)[(size_t)row * N + col] = acc[mt][i] + bb;
            }
    } else {
        const int cl = w * 16 + (lane & 15);            // block-local col
        #pragma unroll
        for (int mt = 0; mt < 4; ++mt)
            #pragma unroll
            for (int i = 0; i < 4; ++i)
                tile[cl][mt * 16 + rq + i] = f2bf(acc[mt][i] + bb);
        __syncthreads();
        // linear 8KB store: out element (s*GG + col0)*64 + c*64 + b
        const int c = tid >> 2, b0 = (tid & 3) << 4;
        unsigned short* dst = (unsigned short*)Cout +
            ((size_t)blockIdx.y * GG + (size_t)blockIdx.x * 64) * 64 + (size_t)tid * 16;
        const uint4* s4 = reinterpret_cast<const uint4*>(&tile[c][b0]);
        reinterpret_cast<uint4*>(dst)[0] = s4[0];
        reinterpret_cast<uint4*>(dst)[1] = s4[1];
    }
}

// Zero h0 for both layers + done flags (8192) + go replicas (1024).
__global__ void zero_init(unsigned short* __restrict__ h0a,
                          unsigned short* __restrict__ h0b,
                          unsigned int* __restrict__ flags) {
    int i = blockIdx.x * 256 + threadIdx.x;      // grid 64 x 256
    for (int k = i; k < BB * HH; k += 64 * 256) { h0a[k] = 0; h0b[k] = 0; }
    for (int k = i; k < 9216; k += 64 * 256) flags[k] = 0;
}

// Fused two-layer persistent LSTM. Grid 512 x 256 (cooperative, 2 blocks/CU).
// Block b: L = b>=256, inner = b&255, g = inner>>1 (h-colgroup), hf = inner&1.
// done[L][hf][128] 16-u32-padded lines; go replicas at +8192:
// go[(L*2+hf)][r] for r in [0,16), each a 16-u32 line. Block polls r = g&15.
// Go value v <=> that layer+domain completed steps 0..v-1.
__global__ __launch_bounds__(256, 2) void lstm_fused(
    const unsigned short* __restrict__ x4s,   // layer-0 input proj (s-major x4)
    const unsigned short* __restrict__ wh0p, const unsigned short* __restrict__ wh1p,
    const unsigned short* __restrict__ wx1p,  // pack_wh layout
    const float* __restrict__ b1,
    unsigned short* __restrict__ hb0, unsigned short* __restrict__ hb1,
    unsigned short* __restrict__ hb2, unsigned short* __restrict__ hb3,
    unsigned int* __restrict__ flags) {
    __shared__ float gx[2][32][36];                         // [khalf][n][block-row]
    __shared__ __align__(16) unsigned short hlds[32][8];    // gathered h chunks
    __shared__ __align__(16) unsigned short Blds[64 * 64 * 8];  // 64 KB Wh slice
    const int tid = threadIdx.x, lane = tid & 63, w = tid >> 6;
    const int L = (blockIdx.x >= 256) ? 1 : 0;
    const int inner = blockIdx.x & 255;
    const int g = inner >> 1, hf = inner & 1;
    unsigned int* done   = flags + L * 4096 + hf * 2048;            // 128 x 16
    unsigned int* go_own = flags + 8192 + (L * 2 + hf) * 256;       // 16 lines
    unsigned int* go_oth = flags + 8192 + ((1 - L) * 2 + hf) * 256;
    const int rep = (g & 15) * 16;                                  // replica line

    // ---- stage this colgroup's Wh slice (64 KB) into LDS, once ----
    {
        const uint4* src = reinterpret_cast<const uint4*>(L ? wh1p : wh0p) + (size_t)g * 4096;
        uint4* dst = reinterpret_cast<uint4*>(Blds);
        #pragma unroll
        for (int i = 0; i < 16; ++i)
            dst[i * 256 + tid] = src[i * 256 + tid];
    }
    __syncthreads();
    const bf16x8* Bl = reinterpret_cast<const bf16x8*>(Blds);
    const bf16x8* Wx = reinterpret_cast<const bf16x8*>(wx1p);

    const int msub = w & 1, kh = w >> 1;
    const int kh16 = kh * 16;
    const int nloc = lane & 15;
    const int cj = nloc & 7;
    const int q0 = nloc >> 3;                               // gate idx for nt=0
    const int gq0 = q0 * HH + 8 * g + cj;                   // nt=0 gate col
    const int gq1 = (2 + q0) * HH + 8 * g + cj;             // nt=1 gate col
    const int rbase = msub * 16 + ((lane >> 4) << 2);       // block-local row base
    const size_t afrag_base = ((size_t)(2 * hf + msub) * 32 + (size_t)kh * 16) * 64 + lane;
    const int row_l = tid >> 3, cj2 = tid & 7;
    float c = 0.f;

    if (L == 0) {
        // =================== layer 0 ===================
        ushort4 xv0 = {0, 0, 0, 0}, xv1 = {0, 0, 0, 0};
        if (kh == 0) {
            xv0 = *reinterpret_cast<const ushort4*>(x4s + ((size_t)gq0) * 64 + 32 * hf + rbase);
            xv1 = *reinterpret_cast<const ushort4*>(x4s + ((size_t)gq1) * 64 + 32 * hf + rbase);
        }
        #pragma unroll 1
        for (int t = 0; t < SS; ++t) {
            // gates (all-thread, replicated lines): own done t-1; L1 done t-2
            if (t > 0) {
                gate_poll(&go_own[rep], (unsigned)t);
                if (t >= 2) gate_poll(&go_oth[rep], (unsigned)(t - 1));
            }
            const unsigned long long* hv =
                reinterpret_cast<const unsigned long long*>((t & 1) ? hb1 : hb0);
            unsigned short* hout = (t & 1) ? hb0 : hb1;

            bf16x8 A[16];
            #pragma unroll
            for (int k = 0; k < 16; ++k)
                A[k] = ld_frag_coh(hv + (afrag_base + (size_t)k * 64) * 2);

            f32x4 acc0 = {0.f, 0.f, 0.f, 0.f}, acc1 = {0.f, 0.f, 0.f, 0.f};
            #pragma unroll
            for (int k = 0; k < 16; ++k) {
                acc0 = __builtin_amdgcn_mfma_f32_16x16x32_bf16(
                    A[k], Bl[(kh16 + k) * 64 + lane], acc0, 0, 0, 0);
                acc1 = __builtin_amdgcn_mfma_f32_16x16x32_bf16(
                    A[k], Bl[(32 + kh16 + k) * 64 + lane], acc1, 0, 0, 0);
            }
            if (kh == 0) {
                gx[0][nloc][rbase + 0] = acc0[0] + bf2f(xv0.x);
                gx[0][nloc][rbase + 1] = acc0[1] + bf2f(xv0.y);
                gx[0][nloc][rbase + 2] = acc0[2] + bf2f(xv0.z);
                gx[0][nloc][rbase + 3] = acc0[3] + bf2f(xv0.w);
                gx[0][16 + nloc][rbase + 0] = acc1[0] + bf2f(xv1.x);
                gx[0][16 + nloc][rbase + 1] = acc1[1] + bf2f(xv1.y);
                gx[0][16 + nloc][rbase + 2] = acc1[2] + bf2f(xv1.z);
                gx[0][16 + nloc][rbase + 3] = acc1[3] + bf2f(xv1.w);
            } else {
                gx[1][nloc][rbase + 0] = acc0[0];
                gx[1][nloc][rbase + 1] = acc0[1];
                gx[1][nloc][rbase + 2] = acc0[2];
                gx[1][nloc][rbase + 3] = acc0[3];
                gx[1][16 + nloc][rbase + 0] = acc1[0];
                gx[1][16 + nloc][rbase + 1] = acc1[1];
                gx[1][16 + nloc][rbase + 2] = acc1[2];
                gx[1][16 + nloc][rbase + 3] = acc1[3];
            }
            __syncthreads();

            float gi = gx[0][0 * 8 + cj2][row_l] + gx[1][0 * 8 + cj2][row_l];
            float gf = gx[0][1 * 8 + cj2][row_l] + gx[1][1 * 8 + cj2][row_l];
            float gg = gx[0][2 * 8 + cj2][row_l] + gx[1][2 * 8 + cj2][row_l];
            float go = gx[0][3 * 8 + cj2][row_l] + gx[1][3 * 8 + cj2][row_l];
            float cn = sigm(gf) * c + sigm(gi) * tanhf(gg);
            c = cn;
            hlds[row_l][cj2] = f2bf(sigm(go) * tanhf(cn));
            __syncthreads();

            if (tid < 32) {
                union { uint4 v; unsigned long long u[2]; } cv;
                cv.v = *reinterpret_cast<const uint4*>(&hlds[tid][0]);
                const int m = 32 * hf + tid;
                unsigned long long* dst = reinterpret_cast<unsigned long long*>(
                    hout + (((size_t)(m >> 4) * 32 + (g >> 2)) * 64 + (g & 3) * 16 + (m & 15)) * 8);
                __hip_atomic_store(dst,     cv.u[0], __ATOMIC_RELAXED, __HIP_MEMORY_SCOPE_AGENT);
                __hip_atomic_store(dst + 1, cv.u[1], __ATOMIC_RELAXED, __HIP_MEMORY_SCOPE_AGENT);
            }
            if (w == 0)
                asm volatile("s_waitcnt vmcnt(0)" ::: "memory");   // wave-0 stores only
            if (tid == 0)
                __hip_atomic_store(&done[g * 16], (unsigned)(t + 1),
                                   __ATOMIC_RELAXED, __HIP_MEMORY_SCOPE_AGENT);
            // off-path: next-step xv prefetch
            if (kh == 0 && t + 1 < SS) {
                xv0 = *reinterpret_cast<const ushort4*>(
                    x4s + ((size_t)(t + 1) * GG + gq0) * 64 + 32 * hf + rbase);
                xv1 = *reinterpret_cast<const ushort4*>(
                    x4s + ((size_t)(t + 1) * GG + gq1) * 64 + 32 * hf + rbase);
            }
            // leader: observe 128 done-flags, publish 16 go replicas
            if (g == 0 && tid < 64) {
                const unsigned tgt = (unsigned)(t + 1);
                unsigned v0 = 0, v1 = 0;
                while (1) {
                    if (v0 < tgt)
                        v0 = __hip_atomic_load(&done[tid * 16], __ATOMIC_RELAXED,
                                               __HIP_MEMORY_SCOPE_AGENT);
                    if (v1 < tgt)
                        v1 = __hip_atomic_load(&done[(tid + 64) * 16], __ATOMIC_RELAXED,
                                               __HIP_MEMORY_SCOPE_AGENT);
                    if (__all((v0 >= tgt) && (v1 >= tgt))) break;
                    __builtin_amdgcn_s_sleep(1);
                }
                if (tid < 16)
                    __hip_atomic_store(&go_own[tid * 16], tgt, __ATOMIC_RELAXED,
                                       __HIP_MEMORY_SCOPE_AGENT);
            }
        }
    } else {
        // =================== layer 1 (lag 1; fused x-projection) =============
        const float bb0 = b1[gq0], bb1 = b1[gq1];
        #pragma unroll 1
        for (int t = 0; t < SS; ++t) {
            // cross-gate FIRST (steady state: already satisfied, L0 leads)
            gate_poll(&go_oth[rep], (unsigned)(t + 1));
            // issue h1(t) fragment loads immediately -- fly during own-gate
            const unsigned long long* hv1 =
                reinterpret_cast<const unsigned long long*>((t & 1) ? hb0 : hb1);
            bf16x8 A1[16];
            #pragma unroll
            for (int k = 0; k < 16; ++k)
                A1[k] = ld_frag_coh(hv1 + (afrag_base + (size_t)k * 64) * 2);

            // own-gate: all siblings completed step t-1 (h2(t-1) fully stored)
            if (t > 0)
                gate_poll(&go_own[rep], (unsigned)t);
            const unsigned long long* hv2 =
                reinterpret_cast<const unsigned long long*>((t & 1) ? hb3 : hb2);
            unsigned short* hout2 = (t & 1) ? hb2 : hb3;
            bf16x8 A2[16];
            #pragma unroll
            for (int k = 0; k < 16; ++k)
                A2[k] = ld_frag_coh(hv2 + (afrag_base + (size_t)k * 64) * 2);

            f32x4 acc0 = {0.f, 0.f, 0.f, 0.f}, acc1 = {0.f, 0.f, 0.f, 0.f};
            // x-projection first (A2's IF window hides under these MFMAs)
            {
                bf16x8 BXa[8], BXb[8];
                #pragma unroll
                for (int j = 0; j < 8; ++j) {
                    BXa[j] = Wx[((size_t)(g * 64 + kh16 + j)) * 64 + lane];
                    BXb[j] = Wx[((size_t)(g * 64 + 32 + kh16 + j)) * 64 + lane];
                }
                #pragma unroll
                for (int j = 0; j < 8; ++j) {
                    acc0 = __builtin_amdgcn_mfma_f32_16x16x32_bf16(A1[j], BXa[j], acc0, 0, 0, 0);
                    acc1 = __builtin_amdgcn_mfma_f32_16x16x32_bf16(A1[j], BXb[j], acc1, 0, 0, 0);
                }
                #pragma unroll
                for (int j = 0; j < 8; ++j) {
                    BXa[j] = Wx[((size_t)(g * 64 + kh16 + 8 + j)) * 64 + lane];
                    BXb[j] = Wx[((size_t)(g * 64 + 32 + kh16 + 8 + j)) * 64 + lane];
                }
                #pragma unroll
                for (int j = 0; j < 8; ++j) {
                    acc0 = __builtin_amdgcn_mfma_f32_16x16x32_bf16(A1[8 + j], BXa[j], acc0, 0, 0, 0);
                    acc1 = __builtin_amdgcn_mfma_f32_16x16x32_bf16(A1[8 + j], BXb[j], acc1, 0, 0, 0);
                }
            }
            // recurrent GEMM (A2 long since landed)
            #pragma unroll
            for (int k = 0; k < 16; ++k) {
                acc0 = __builtin_amdgcn_mfma_f32_16x16x32_bf16(
                    A2[k], Bl[(kh16 + k) * 64 + lane], acc0, 0, 0, 0);
                acc1 = __builtin_amdgcn_mfma_f32_16x16x32_bf16(
                    A2[k], Bl[(32 + kh16 + k) * 64 + lane], acc1, 0, 0, 0);
            }

            if (kh == 0) {
                gx[0][nloc][rbase + 0] = acc0[0] + bb0;
                gx[0][nloc][rbase + 1] = acc0[1] + bb0;
                gx[0][nloc][rbase + 2] = acc0[2] + bb0;
                gx[0][nloc][rbase + 3] = acc0[3] + bb0;
                gx[0][16 + nloc][rbase + 0] = acc1[0] + bb1;
                gx[0][16 + nloc][rbase + 1] = acc1[1] + bb1;
                gx[0][16 + nloc][rbase + 2] = acc1[2] + bb1;
                gx[0][16 + nloc][rbase + 3] = acc1[3] + bb1;
            } else {
                gx[1][nloc][rbase + 0] = acc0[0];
                gx[1][nloc][rbase + 1] = acc0[1];
                gx[1][nloc][rbase + 2] = acc0[2];
                gx[1][nloc][rbase + 3] = acc0[3];
                gx[1][16 + nloc][rbase + 0] = acc1[0];
                gx[1][16 + nloc][rbase + 1] = acc1[1];
                gx[1][16 + nloc][rbase + 2] = acc1[2];
                gx[1][16 + nloc][rbase + 3] = acc1[3];
            }
            __syncthreads();

            float gi = gx[0][0 * 8 + cj2][row_l] + gx[1][0 * 8 + cj2][row_l];
            float gf = gx[0][1 * 8 + cj2][row_l] + gx[1][1 * 8 + cj2][row_l];
            float gg = gx[0][2 * 8 + cj2][row_l] + gx[1][2 * 8 + cj2][row_l];
            float go = gx[0][3 * 8 + cj2][row_l] + gx[1][3 * 8 + cj2][row_l];
            float cn = sigm(gf) * c + sigm(gi) * tanhf(gg);
            c = cn;
            hlds[row_l][cj2] = f2bf(sigm(go) * tanhf(cn));
            __syncthreads();

            if (tid < 32) {
                union { uint4 v; unsigned long long u[2]; } cv;
                cv.v = *reinterpret_cast<const uint4*>(&hlds[tid][0]);
                const int m = 32 * hf + tid;
                unsigned long long* dst = reinterpret_cast<unsigned long long*>(
                    hout2 + (((size_t)(m >> 4) * 32 + (g >> 2)) * 64 + (g & 3) * 16 + (m & 15)) * 8);
                __hip_atomic_store(dst,     cv.u[0], __ATOMIC_RELAXED, __HIP_MEMORY_SCOPE_AGENT);
                __hip_atomic_store(dst + 1, cv.u[1], __ATOMIC_RELAXED, __HIP_MEMORY_SCOPE_AGENT);
            }
            if (w == 0)
                asm volatile("s_waitcnt vmcnt(0)" ::: "memory");
            if (tid == 0)
                __hip_atomic_store(&done[g * 16], (unsigned)(t + 1),
                                   __ATOMIC_RELAXED, __HIP_MEMORY_SCOPE_AGENT);
            if (g == 0 && tid < 64) {
                const unsigned tgt = (unsigned)(t + 1);
                unsigned v0 = 0, v1 = 0;
                while (1) {
                    if (v0 < tgt)
                        v0 = __hip_atomic_load(&done[tid * 16], __ATOMIC_RELAXED,
                                               __HIP_MEMORY_SCOPE_AGENT);
                    if (v1 < tgt)
                        v1 = __hip_atomic_load(&done[(tid + 64) * 16], __ATOMIC_RELAXED,
                                               __HIP_MEMORY_SCOPE_AGENT);
                    if (__all((v0 >= tgt) && (v1 >= tgt))) break;
                    __builtin_amdgcn_s_sleep(1);
                }
                if (tid < 16)
                    __hip_atomic_store(&go_own[tid * 16], tgt, __ATOMIC_RELAXED,
                                       __HIP_MEMORY_SCOPE_AGENT);
            }
        }
    }
}

__global__ __launch_bounds__(256) void softmax_rows(const float* __restrict__ logits,
                                                    float* __restrict__ out) {
    __shared__ float red[256];
    int rr = blockIdx.x, tid = threadIdx.x;
    const float* L = logits + (size_t)rr * VV;
    float m = -1e30f;
    for (int i = tid; i < VV; i += 256) m = fmaxf(m, L[i]);
    red[tid] = m; __syncthreads();
    for (int s = 128; s > 0; s >>= 1) { if (tid < s) red[tid] = fmaxf(red[tid], red[tid + s]); __syncthreads(); }
    m = red[0]; __syncthreads();
    float sum = 0.f;
    for (int i = tid; i < VV; i += 256) sum += expf(L[i] - m);
    red[tid] = sum; __syncthreads();
    for (int s = 128; s > 0; s >>= 1) { if (tid < s) red[tid] += red[tid + s]; __syncthreads(); }
    float inv = 1.f / red[0];
    for (int i = tid; i < VV; i += 256) out[(size_t)rr * VV + i] = expf(L[i] - m) * inv;
}

extern "C" void kernel_launch(void* const* d_in, const int* in_sizes, int n_in,
                              void* d_out, int out_size, void* d_ws, size_t ws_size,
                              hipStream_t stream) {
    const int*   x    = (const int*)  d_in[0];
    const float* tab  = (const float*)d_in[1];
    const float* Wx0  = (const float*)d_in[2];
    const float* Wh0  = (const float*)d_in[3];
    const float* b0   = (const float*)d_in[4];
    const float* Wx1  = (const float*)d_in[5];
    const float* Wh1  = (const float*)d_in[6];
    const float* b1   = (const float*)d_in[7];
    const float* Wout = (const float*)d_in[8];
    const float* bout = (const float*)d_in[9];
    float* out = (float*)d_out;

    // ---- workspace layout (ushort units); all segments 16B-aligned ----
    unsigned short* ws    = (unsigned short*)d_ws;
    unsigned short* embA  = ws;                    // 16,777,216
    unsigned short* wx0p  = embA  + 16777216;      //  2,097,152
    unsigned short* wh0p  = wx0p  + 2097152;       //  4,194,304
    unsigned short* wx1p  = wh0p  + 4194304;       //  4,194,304 (pack_wh layout)
    unsigned short* wh1p  = wx1p  + 4194304;       //  4,194,304
    unsigned short* woutp = wh1p  + 4194304;       // 32,768,000
    unsigned short* x4s   = woutp + 32768000;      // 134,217,728 (layer-0 only)
    unsigned short* h1A   = x4s   + 134217728;     // 33,554,432 (unused now)
    unsigned short* hb0   = h1A   + 33554432;      // 65,536  (layer 0)
    unsigned short* hb1   = hb0   + 65536;         // 65,536
    unsigned short* hb2   = hb1   + 65536;         // 65,536  (layer 1)
    unsigned short* hb3   = hb2   + 65536;         // 65,536
    float* logits = (float*)(hb3 + 65536);         // 2,048,000 f32
    unsigned int* flags = (unsigned int*)(logits + 2048000);  // 8192 done + 1024 go
    // total ~472 MB

    // ---- weight packing ----
    pack_b <<<256 * 16, 64, 0, stream>>>(Wx0, wx0p, 16, GG);
    pack_wh<<<8192, 64, 0, stream>>>(Wh0, wh0p);
    pack_wh<<<8192, 64, 0, stream>>>(Wx1, wx1p);   // per-colgroup slice layout
    pack_wh<<<8192, 64, 0, stream>>>(Wh1, wh1p);
    pack_b <<<2000 * 32, 64, 0, stream>>>(Wout, woutp, 32, VV);

    // ---- h0 + flag init ----
    zero_init<<<64, 256, 0, stream>>>(hb0, hb2, flags);

    // ---- embedding + layer-0 input projection ----
    embed_pack<<<32768, 64, 0, stream>>>(x, tab, embA);
    gemm_bias<1><<<dim3(GG / 64, 32768 / 64), 256, 0, stream>>>(embA, wx0p, b0, x4s, GG, EE / 32);

    // ---- fused two-layer recurrence (persistent cooperative, 512 blocks) ----
    {
        const unsigned short* a0 = x4s;
        const unsigned short* a1 = wh0p; const unsigned short* a2 = wh1p;
        const unsigned short* a3 = wx1p; const float* a4 = b1;
        unsigned short *a5 = hb0, *a6 = hb1, *a7 = hb2, *a8 = hb3;
        unsigned int* a9 = flags;
        void* args[] = {&a0, &a1, &a2, &a3, &a4, &a5, &a6, &a7, &a8, &a9};
        hipLaunchCooperativeKernel((const void*)lstm_fused, dim3(512), dim3(256),
                                   args, 0, stream);
    }
    // t=511 (odd) writes layer-1 h into hb2

    // ---- logits (last timestep) + softmax ----
    gemm_bias<0><<<dim3(VV / 64, 1), 256, 0, stream>>>(hb2, woutp, bout, logits, VV, HH / 32);
    softmax_rows<<<64, 256, 0, stream>>>(logits, out);
}